// Round 10
// baseline (213.049 us; speedup 1.0000x reference)
//
#include <hip/hip_runtime.h>
#include <math.h>

// HarmonicCQT via f16 MFMA: out[b,t,k] = |sum_n xpad[t*512+n] * (kr[k,n]+i*ki[k,n])|
//
// Path A (ws >= ~10.8MB), 2 dispatches:
//   1. prep_fused : fp32 audio -> padded f16 xp + B-fragment pack (16-bin
//                   chunks, x4096 pre-scale, verified R3-R9 layout) + zero
//                   acc & arrival counters
//   2. cqt_mfma8  : async-DMA double-buffered MFMA K-loop (verified R9
//                   structure), 19 balanced K-slices -> 836 WGs (~3/CU),
//                   guarded atomic split-K combine, then last-WG-per-(fb,b)
//                   fused magnitude sweep direct to out (no mag dispatch).
// Path B (ws >= ~7.7MB): round-3 LDS-staging MFMA kernel (verified, ~224us).
// Path C: verified fp32 kernel (~370us).
//
// MFMA 16x16x32 layouts (verified rounds 3-9, absmax 4.9e-4):
//   A[m=lane&15][k=(lane>>4)*8+j], B[k=(lane>>4)*8+j][n=lane&15],
//   C/D: col=lane&15, row=(lane>>4)*4+reg.
// bp layout per 16-bin chunk (32 K-cols): 2048B = [64 lanes x 16B re][64 x 16B im]
// global_load_lds: per-lane GLOBAL gather ok; LDS side wave-uniform base,
// lane l lands at base + l*16 (guide m97/m104/m108).

namespace {
constexpr int kSR    = 22050;
constexpr int kHop   = 512;
constexpr int kBins  = 168;
constexpr int kT     = 689;
constexpr int kB     = 4;
constexpr int kS     = 352768;
constexpr float kKScale    = 4096.0f;
constexpr float kKScaleInv = 1.0f / 4096.0f;
constexpr int kG16 = 11;              // 16-bin groups (g10 = bins 160..167)
constexpr int kAcc = kB * kT * kBins * 2;   // unpadded split-K accumulator
constexpr int kCnt = 64;              // arrival counters (44 used)
// path B layout
constexpr int kTPadB   = 768;
constexpr int kBinPadB = 176;
constexpr int kAccB    = kB * kTPadB * kBinPadB * 2;
}

typedef _Float16 half8 __attribute__((ext_vector_type(8)));
typedef _Float16 half2v __attribute__((ext_vector_type(2)));
typedef float floatx4 __attribute__((ext_vector_type(4)));

struct Jobs {          // path B job table
  int k0[48];
  int lo[48];
  int hi[48];
  int n;
};

struct JobsC {         // path A tables
  int lo16[kG16];      // support start col per 16-bin group (256-aligned)
  int cb16[kG16];      // chunk-prefix per group (bp indexing)
  int mlo[3];          // macro-group (64-bin) support start col
  int sm[24];          // per slice: macro id
  int slo[24];         // per slice: chunk range [slo,shi) rel. to mlo (even)
  int shi[24];
  int ns;
  int totch;
};

__device__ inline void atomAddF(float* p, float v) {
  __hip_atomic_fetch_add(p, v, __ATOMIC_RELAXED, __HIP_MEMORY_SCOPE_AGENT);
}

typedef __attribute__((address_space(3))) unsigned int lds_uint;
typedef __attribute__((address_space(1))) const unsigned int glb_uint;
__device__ __forceinline__ void dma16(const void* g, void* l) {
  __builtin_amdgcn_global_load_lds((glb_uint*)g, (lds_uint*)l, 16, 0, 0);
}

// ---- fused prep: [0,nbx) audio | [nbx,nbx+nbp) bpack | rest zero acc+cnt ----
__global__ __launch_bounds__(256) void prep_fused(
    const float* __restrict__ x, const float* __restrict__ kr,
    const float* __restrict__ ki, _Float16* __restrict__ xp,
    _Float16* __restrict__ bp, float* __restrict__ accb,
    const int pad, const int xps, const int nmax,
    const int nbx, const int nbp, const JobsC jt) {
  int bid = blockIdx.x;
  const int tid = threadIdx.x;

  if (bid < nbx) {
    // --- padded f16 audio ---
    const int halfx = xps >> 1;
    const int gid = bid * 256 + tid;
    if (gid >= kB * halfx) return;
    const int b = gid / halfx;
    const int i = (gid - b * halfx) * 2;
    float v0 = 0.f, v1 = 0.f;
    if (i     >= pad && i     < pad + kS) v0 = x[(size_t)b * kS + (i - pad)];
    if (i + 1 >= pad && i + 1 < pad + kS) v1 = x[(size_t)b * kS + (i + 1 - pad)];
    half2v h; h.x = (_Float16)v0; h.y = (_Float16)v1;
    *(half2v*)&xp[(size_t)b * xps + i] = h;
    return;
  }
  bid -= nbx;

  if (bid < nbp) {
    // --- B-fragment pack: 64 threads -> one 16-bin chunk (re+im) ---
    const int chunkid = bid * 4 + (tid >> 6);
    const int lane = tid & 63;
    if (chunkid >= jt.totch) return;
    int g = 0;
    #pragma unroll
    for (int j = 1; j < kG16; ++j)
      if (chunkid >= jt.cb16[j]) g = j;
    const int c = chunkid - jt.cb16[g];
    const int mm = lane & 15;
    const int q  = lane >> 4;
    const int bin  = g * 16 + mm;
    const int col0 = jt.lo16[g] + c * 32 + q * 8;
    const bool binok = (bin < kBins);
    const float* rowr = kr + (size_t)bin * nmax;
    const float* rowi = ki + (size_t)bin * nmax;
    half8 hre, him;
    #pragma unroll
    for (int j = 0; j < 8; ++j) {
      const int col = col0 + j;
      const bool ok = binok && (col < nmax);
      hre[j] = ok ? (_Float16)(rowr[col] * kKScale) : (_Float16)0.f;
      him[j] = ok ? (_Float16)(rowi[col] * kKScale) : (_Float16)0.f;
    }
    _Float16* dst = bp + (size_t)chunkid * 1024 + lane * 8;
    *(half8*)dst = hre;
    *(half8*)(dst + 512) = him;
    return;
  }
  bid -= nbp;

  // --- zero split-K accumulator + arrival counters (counters follow acc) ---
  const int idx = (bid * 256 + tid) * 4;
  if (idx < kAcc + kCnt)
    *(floatx4*)&accb[idx] = (floatx4){0.f, 0.f, 0.f, 0.f};
}

// ---- path A main: async-DMA double-buffered MFMA + fused last-WG finalize ----
// LDS per buffer (halfs): A regions [cc(2)][tl(4)] x 512 at 0..4095;
//                         B regions [wave(4)][cc(2)][re/im] x 512 at 4096..12287.
__global__ __launch_bounds__(256) void cqt_mfma8(
    const _Float16* __restrict__ bp, const _Float16* __restrict__ xp,
    float* __restrict__ accb, int* __restrict__ cnt,
    float* __restrict__ out, const int xps, const JobsC jt) {
  __shared__ _Float16 lds[2][12288];   // 2 x 24 KB
  __shared__ int lastFlag;

  const int sx = blockIdx.y;
  const int fb = blockIdx.x >> 2;      // 0..10
  const int b  = blockIdx.x & 3;
  const int tid  = threadIdx.x;
  const int wave = tid >> 6;
  const int lane = tid & 63;
  const int mm = lane & 15;
  const int q  = lane >> 4;
  const int mac = jt.sm[sx];
  const int g16 = mac * 4 + wave;
  const bool gvalid = (g16 < kG16);
  const int mlo = jt.mlo[mac];
  const int gs = gvalid ? ((jt.lo16[g16] - mlo) >> 5) : 0x7fffffff;
  const int slo = jt.slo[sx];
  const int shi = jt.shi[sx];
  const int fbase = fb * 64;

  // A-DMA source geometry for this wave's 2 staging insts (idx = wave*2+j)
  const _Float16* xb = xp + (size_t)b * xps;
  const int i0 = wave * 2;
  int aoff[2];
  #pragma unroll
  for (int j = 0; j < 2; ++j) {
    const int idx = i0 + j;
    const int tl = idx & 3;
    int row = fbase + tl * 16 + mm;
    if (row > kT - 1) row = kT - 1;
    aoff[j] = row * kHop + q * 8 + ((idx >> 2) * 32);
  }
  const _Float16* bgrp =
      gvalid ? (bp + (size_t)(jt.cb16[g16] - gs) * 1024 + lane * 8) : bp;

  floatx4 accr[4], acci[4];
  #pragma unroll
  for (int tl = 0; tl < 4; ++tl) {
    accr[tl] = (floatx4){0.f, 0.f, 0.f, 0.f};
    acci[tl] = (floatx4){0.f, 0.f, 0.f, 0.f};
  }

  auto stageDMA = [&](int c, int buf) {
    _Float16* L = lds[buf];
    #pragma unroll
    for (int j = 0; j < 2; ++j)
      dma16(xb + mlo + c * 32 + aoff[j], L + (i0 + j) * 512);
    if (gvalid && c >= gs) {
      const _Float16* bs = bgrp + (size_t)c * 1024;
      #pragma unroll
      for (int cc = 0; cc < 2; ++cc)
        #pragma unroll
        for (int ri = 0; ri < 2; ++ri)
          dma16(bs + cc * 1024 + ri * 512,
                L + 4096 + (wave * 4 + cc * 2 + ri) * 512);
    }
  };

  auto compute = [&](int c, int buf) {
    if (!gvalid || c < gs) return;
    const _Float16* L = lds[buf];
    #pragma unroll
    for (int cc = 0; cc < 2; ++cc) {
      const half8 Bre = *(const half8*)(L + 4096 + (wave * 4 + cc * 2) * 512 + lane * 8);
      const half8 Bim = *(const half8*)(L + 4096 + (wave * 4 + cc * 2 + 1) * 512 + lane * 8);
      #pragma unroll
      for (int tl = 0; tl < 4; ++tl) {
        const half8 A = *(const half8*)(L + (cc * 4 + tl) * 512 + lane * 8);
        accr[tl] = __builtin_amdgcn_mfma_f32_16x16x32_f16(A, Bre, accr[tl], 0, 0, 0);
        acci[tl] = __builtin_amdgcn_mfma_f32_16x16x32_f16(A, Bim, acci[tl], 0, 0, 0);
      }
    }
  };

  // 2-barrier double-buffered pipeline (verified R9)
  stageDMA(slo, 0);
  int buf = 0;
  #pragma unroll 1
  for (int c = slo; c < shi; c += 2) {
    __syncthreads();                       // drains this stage's DMA (vmcnt)
    if (c + 2 < shi) stageDMA(c + 2, buf ^ 1);
    compute(c, buf);
    buf ^= 1;
  }

  // epilogue: un-scale + guarded split-K atomic combine (verified R8/R9)
  const int bin = g16 * 16 + mm;
  if (bin < kBins) {
    #pragma unroll
    for (int tl = 0; tl < 4; ++tl) {
      const int tb = fbase + tl * 16 + q * 4;
      #pragma unroll
      for (int r = 0; r < 4; ++r) {
        const int t = tb + r;
        if (t < kT) {
          const size_t o = (((size_t)b * kT + t) * kBins + bin) * 2;
          atomAddF(&accb[o],     accr[tl][r] * kKScaleInv);
          atomAddF(&accb[o + 1], acci[tl][r] * kKScaleInv);
        }
      }
    }
  }

  // ---- fused finalize: last slice-WG for this (fb,b) sweeps magnitudes ----
  __threadfence();          // make my atomics visible device-wide
  __syncthreads();          // all threads' fences precede tid0's arrival
  if (tid == 0) {
    const int old = __hip_atomic_fetch_add(&cnt[blockIdx.x], 1,
                                           __ATOMIC_ACQ_REL,
                                           __HIP_MEMORY_SCOPE_AGENT);
    lastFlag = (old == (int)gridDim.y - 1);
  }
  __syncthreads();
  if (lastFlag) {
    __threadfence();
    #pragma unroll 1
    for (int i = tid; i < 64 * kBins; i += 256) {
      const int t = fbase + i / kBins;
      const int k = i - (i / kBins) * kBins;
      if (t < kT) {
        const size_t o = (((size_t)b * kT + t) * kBins + k) * 2;
        const float re = __hip_atomic_load(&accb[o], __ATOMIC_RELAXED,
                                           __HIP_MEMORY_SCOPE_AGENT);
        const float im = __hip_atomic_load(&accb[o + 1], __ATOMIC_RELAXED,
                                           __HIP_MEMORY_SCOPE_AGENT);
        out[o >> 1] = sqrtf(re * re + im * im);
      }
    }
  }
}

// ---- final: magnitude (path B only) ----
__global__ __launch_bounds__(256) void cqt_mag_final(
    const float* __restrict__ accb, float* __restrict__ out,
    const int tp, const int kp) {
  int gid = blockIdx.x * 256 + threadIdx.x;
  if (gid >= kB * kT * kBins) return;
  const int k = gid % kBins;
  const int r = gid / kBins;
  const int t = r % kT;
  const int b = r / kT;
  const float2 v = ((const float2*)accb)[((size_t)b * tp + t) * kp + k];
  out[gid] = sqrtf(v.x * v.x + v.y * v.y);
}

// ================= path B: round-3 LDS-staging MFMA (verified) =============
__global__ __launch_bounds__(256) void prep_x_kernel(
    const float* __restrict__ x, _Float16* __restrict__ xp,
    const int pad, const int xps) {
  const int halfx = xps >> 1;
  int gid = blockIdx.x * 256 + threadIdx.x;
  if (gid >= kB * halfx) return;
  const int b = gid / halfx;
  const int i = (gid - b * halfx) * 2;
  float v0 = 0.f, v1 = 0.f;
  if (i     >= pad && i     < pad + kS) v0 = x[(size_t)b * kS + (i - pad)];
  if (i + 1 >= pad && i + 1 < pad + kS) v1 = x[(size_t)b * kS + (i + 1 - pad)];
  half2v h; h.x = (_Float16)v0; h.y = (_Float16)v1;
  *(half2v*)&xp[(size_t)b * xps + i] = h;
}

__global__ __launch_bounds__(256) void cqt_mfma_kernel(
    const float* __restrict__ kr, const float* __restrict__ ki,
    const _Float16* __restrict__ xp, float* __restrict__ accb,
    const int nmax, const int xps, const Jobs jt) {
  __shared__ _Float16 Bs[2][16][264];
  const int jb = blockIdx.x;
  const int k0   = jt.k0[jb];
  const int n_lo = jt.lo[jb];
  const int n_hi = jt.hi[jb];
  const int b  = blockIdx.z;
  const int fb = blockIdx.y;
  const int tid  = threadIdx.x;
  const int lane = tid & 63;
  const int wave = tid >> 6;
  const int m = lane & 15;
  const int q = lane >> 4;
  const int sbin = tid >> 4;
  const int scol = tid & 15;
  const int gbin = k0 + sbin;
  const bool binok = (gbin < kBins);
  const float* rowr = kr + (size_t)gbin * nmax;
  const float* rowi = ki + (size_t)gbin * nmax;
  const int fbase = fb * 256 + wave * 64;
  const _Float16* ax =
      xp + (size_t)b * xps + (size_t)(fbase + m) * kHop + q * 8;
  floatx4 accr[4], acci[4];
  #pragma unroll
  for (int tl = 0; tl < 4; ++tl) {
    accr[tl] = (floatx4){0.f, 0.f, 0.f, 0.f};
    acci[tl] = (floatx4){0.f, 0.f, 0.f, 0.f};
  }
  for (int n0r = n_lo; n0r < n_hi; n0r += 256) {
    __syncthreads();
    #pragma unroll
    for (int c = 0; c < 16; ++c) {
      const int col = n0r + scol + c * 16;
      const bool ok = binok && (col < nmax);
      const float vr = ok ? rowr[col] : 0.f;
      const float vi = ok ? rowi[col] : 0.f;
      Bs[0][sbin][scol + c * 16] = (_Float16)(vr * kKScale);
      Bs[1][sbin][scol + c * 16] = (_Float16)(vi * kKScale);
    }
    __syncthreads();
    const _Float16* axr = ax + n0r;
    #pragma unroll
    for (int c = 0; c < 8; ++c) {
      const int ko = c * 32 + q * 8;
      const half8 br = *(const half8*)&Bs[0][m][ko];
      const half8 bi = *(const half8*)&Bs[1][m][ko];
      #pragma unroll
      for (int tl = 0; tl < 4; ++tl) {
        const half8 a = *(const half8*)(axr + tl * 16 * kHop + c * 32);
        accr[tl] = __builtin_amdgcn_mfma_f32_16x16x32_f16(a, br, accr[tl], 0, 0, 0);
        acci[tl] = __builtin_amdgcn_mfma_f32_16x16x32_f16(a, bi, acci[tl], 0, 0, 0);
      }
    }
  }
  #pragma unroll
  for (int tl = 0; tl < 4; ++tl) {
    #pragma unroll
    for (int rr = 0; rr < 4; ++rr) {
      const int t = fbase + tl * 16 + q * 4 + rr;
      const size_t o = (((size_t)b * kTPadB + t) * kBinPadB + (k0 + m)) * 2;
      atomAddF(&accb[o],     accr[tl][rr] * kKScaleInv);
      atomAddF(&accb[o + 1], acci[tl][rr] * kKScaleInv);
    }
  }
}

// ================= path C: verified fp32 kernel (round 2) ==================
namespace fb32 {
constexpr int TT = 8;
constexpr int KG = 4;
constexpr int kTTiles  = (kT + TT - 1) / TT;
constexpr int kKGroups = kBins / KG;
constexpr int kWaves   = kB * kTTiles * kKGroups;
}

__global__ __launch_bounds__(256) void cqt_mag_kernel(
    const float* __restrict__ x,
    const float* __restrict__ kr,
    const float* __restrict__ ki,
    float* __restrict__ out,
    const int nmax, const int pad) {
  using namespace fb32;
  const int wave = (blockIdx.x << 2) + (threadIdx.x >> 6);
  const int lane = threadIdx.x & 63;
  if (wave >= kWaves) return;
  const int kg    = wave / (kB * kTTiles);
  const int rem   = wave - kg * (kB * kTTiles);
  const int b     = rem / kTTiles;
  const int ttile = rem - b * kTTiles;
  const int k0 = kg * KG;
  const int t0 = ttile * TT;
  const double Q  = 1.0 / (exp2(1.0 / 24.0) - 1.0);
  const double f0 = 32.7 * exp2((double)k0 / 24.0);
  int N = (int)ceil(Q * (double)kSR / f0) + 8;
  int full_start = nmax - N;
  if (full_start < 0) full_start = 0;
  int tbase[TT], lo[TT], t_last;
  { int t = t0 + TT - 1; if (t > kT - 1) t = kT - 1; t_last = t; }
  #pragma unroll
  for (int tt = 0; tt < TT; ++tt) {
    int t = t0 + tt; if (t > kT - 1) t = kT - 1;
    tbase[tt] = b * kS + t * kHop - pad;
    lo[tt]    = pad - t * kHop;
  }
  int head_start = pad - t_last * kHop;
  if (head_start < full_start) head_start = full_start;
  int safe = pad - t0 * kHop;
  if (safe < head_start) safe = head_start;
  int body_start = nmax - ((nmax - safe) & ~63);
  float accr[TT][KG], acci[TT][KG];
  #pragma unroll
  for (int tt = 0; tt < TT; ++tt)
    #pragma unroll
    for (int kk = 0; kk < KG; ++kk) { accr[tt][kk] = 0.f; acci[tt][kk] = 0.f; }
  for (int n = body_start - 64; n > head_start - 64; n -= 64) {
    const int nn = n + lane;
    const bool kok = (nn >= 0);
    float krv[KG], kiv[KG];
    #pragma unroll
    for (int kk = 0; kk < KG; ++kk) {
      krv[kk] = kok ? kr[(k0 + kk) * nmax + nn] : 0.f;
      kiv[kk] = kok ? ki[(k0 + kk) * nmax + nn] : 0.f;
    }
    float a[TT];
    #pragma unroll
    for (int tt = 0; tt < TT; ++tt)
      a[tt] = (nn >= lo[tt]) ? x[tbase[tt] + nn] : 0.f;
    #pragma unroll
    for (int tt = 0; tt < TT; ++tt)
      #pragma unroll
      for (int kk = 0; kk < KG; ++kk) {
        accr[tt][kk] = fmaf(a[tt], krv[kk], accr[tt][kk]);
        acci[tt][kk] = fmaf(a[tt], kiv[kk], acci[tt][kk]);
      }
  }
  for (int n = body_start; n < nmax; n += 64) {
    const int nn = n + lane;
    float krv[KG], kiv[KG];
    #pragma unroll
    for (int kk = 0; kk < KG; ++kk) {
      krv[kk] = kr[(k0 + kk) * nmax + nn];
      kiv[kk] = ki[(k0 + kk) * nmax + nn];
    }
    float a[TT];
    #pragma unroll
    for (int tt = 0; tt < TT; ++tt)
      a[tt] = x[tbase[tt] + nn];
    #pragma unroll
    for (int tt = 0; tt < TT; ++tt)
      #pragma unroll
      for (int kk = 0; kk < KG; ++kk) {
        accr[tt][kk] = fmaf(a[tt], krv[kk], accr[tt][kk]);
        acci[tt][kk] = fmaf(a[tt], kiv[kk], acci[tt][kk]);
      }
  }
  #pragma unroll
  for (int tt = 0; tt < TT; ++tt) {
    #pragma unroll
    for (int kk = 0; kk < KG; ++kk) {
      float r = accr[tt][kk];
      float i = acci[tt][kk];
      #pragma unroll
      for (int s = 32; s > 0; s >>= 1) {
        r += __shfl_xor(r, s, 64);
        i += __shfl_xor(i, s, 64);
      }
      if (lane == 0) {
        const int t = t0 + tt;
        if (t < kT)
          out[(b * kT + t) * kBins + (k0 + kk)] = sqrtf(r * r + i * i);
      }
    }
  }
}
// ============================================================================

extern "C" void kernel_launch(void* const* d_in, const int* in_sizes, int n_in,
                              void* d_out, int out_size, void* d_ws, size_t ws_size,
                              hipStream_t stream) {
  const float* x  = (const float*)d_in[0];   // [4, 1, 352768]
  const float* kr = (const float*)d_in[1];   // [168, nmax]
  const float* ki = (const float*)d_in[2];   // [168, nmax]
  float* out = (float*)d_out;                // [4, 1, 689, 168]

  const int nmax = in_sizes[1] / kBins;      // 23013 (runtime truth)
  const int pad  = nmax - kHop;

  const int kcap = ((nmax + 255) / 256) * 256;   // 23040
  const double Q = 1.0 / (exp2(1.0 / 24.0) - 1.0);

  // ---- path A tables ----
  JobsC jc;
  int tot = 0;
  for (int g = 0; g < kG16; ++g) {
    const double f0 = 32.7 * exp2((double)(16 * g) / 24.0);
    const int N = (int)ceil(Q * (double)kSR / f0) + 8;
    int lo = nmax - N;
    if (lo < 0) lo = 0;
    lo &= ~255;
    jc.lo16[g] = lo;
    jc.cb16[g] = tot;
    tot += (kcap - lo) / 32;
  }
  jc.totch = tot;                        // ~1980 chunks
  const int nsl_m[3] = {15, 3, 1};       // ~48/40/24-chunk slices
  int ns = 0;
  for (int m = 0; m < 3; ++m) {
    jc.mlo[m] = jc.lo16[4 * m];
    const int C = (kcap - jc.mlo[m]) / 32;       // 720 / 120 / 24
    const int nsl = nsl_m[m];
    const int len = ((C + nsl - 1) / nsl + 1) & ~1;
    for (int s = 0; s < nsl && ns < 24; ++s) {
      const int lo = s * len;
      if (lo >= C) break;
      int hi = lo + len;
      if (hi > C) hi = C;
      jc.sm[ns] = m; jc.slo[ns] = lo; jc.shi[ns] = hi;
      ++ns;
    }
  }
  jc.ns = ns;                            // 19 expected

  // ---- path A ws layout ----
  const int xpsA = (kT - 1) * kHop + kcap + 256;           // 375,552
  const size_t xpA_bytes = (size_t)kB * xpsA * sizeof(_Float16);
  const size_t accA_off  = (xpA_bytes + 511) & ~(size_t)511;
  const size_t accA_bytes = (size_t)(kAcc + kCnt) * sizeof(float);
  const size_t bpA_off   = (accA_off + accA_bytes + 511) & ~(size_t)511;
  const size_t bpA_bytes = (size_t)tot * 2048;
  const size_t ws_A = bpA_off + bpA_bytes;                 // ~10.8 MB

  // ---- path B layout ----
  const int xpsB = (kTPadB - 1) * kHop + kcap + 256;
  const size_t xpB_bytes = (size_t)kB * xpsB * sizeof(_Float16);
  const size_t accB_off  = (xpB_bytes + 511) & ~(size_t)511;
  const size_t accB_bytes = (size_t)kAccB * sizeof(float);
  const size_t ws_B = accB_off + accB_bytes;

  if (ws_size >= ws_A) {
    // ---- path A: 2 dispatches ----
    _Float16* xp = (_Float16*)d_ws;
    float* accb  = (float*)((char*)d_ws + accA_off);
    int* cnt     = (int*)(accb + kAcc);
    _Float16* bp = (_Float16*)((char*)d_ws + bpA_off);

    const int nbx = (kB * (xpsA / 2) + 255) / 256;   // audio blocks
    const int nbp = (tot + 3) / 4;                   // bpack blocks (4 chunks ea)
    const int nba = ((kAcc + kCnt) / 4 + 255) / 256; // acc+cnt zero blocks
    prep_fused<<<nbx + nbp + nba, 256, 0, stream>>>(
        x, kr, ki, xp, bp, accb, pad, xpsA, nmax, nbx, nbp, jc);

    {
      dim3 grid(44, ns);   // x = fb(11) * b(4); y = balanced K-slices
      cqt_mfma8<<<grid, 256, 0, stream>>>(bp, xp, accb, cnt, out, xpsA, jc);
    }
    return;
  }

  if (ws_size >= ws_B) {
    // ---- path B (round-3, verified ~224us) ----
    _Float16* xp = (_Float16*)d_ws;
    float* accb  = (float*)((char*)d_ws + accB_off);
    Jobs jt;
    int nj = 0;
    for (int g = 0; g < 11; ++g) {
      const int gk0 = 16 * g;
      const double f0 = 32.7 * exp2((double)gk0 / 24.0);
      const int N = (int)ceil(Q * (double)kSR / f0) + 8;
      int lo = nmax - N;
      if (lo < 0) lo = 0;
      lo = (lo / 2048) * 2048;
      for (int s = lo; s < kcap && nj < 48; s += 2048) {
        jt.k0[nj] = gk0;
        jt.lo[nj] = s;
        jt.hi[nj] = (s + 2048 < kcap) ? s + 2048 : kcap;
        ++nj;
      }
    }
    jt.n = nj;
    hipMemsetAsync(accb, 0, accB_bytes, stream);
    {
      const int total = kB * (xpsB / 2);
      prep_x_kernel<<<(total + 255) / 256, 256, 0, stream>>>(x, xp, pad, xpsB);
    }
    {
      dim3 grid(nj, kTPadB / 256, kB);
      cqt_mfma_kernel<<<grid, 256, 0, stream>>>(kr, ki, xp, accb, nmax, xpsB, jt);
    }
    {
      const int total = kB * kT * kBins;
      cqt_mag_final<<<(total + 255) / 256, 256, 0, stream>>>(
          accb, out, kTPadB, kBinPadB);
    }
    return;
  }

  // ---- path C: fp32 fallback ----
  {
    const int blocks = fb32::kWaves / 4;
    cqt_mag_kernel<<<blocks, 256, 0, stream>>>(x, kr, ki, out, nmax, pad);
  }
}

// Round 11
// 152.416 us; speedup vs baseline: 1.3978x; 1.3978x over previous
//
#include <hip/hip_runtime.h>
#include <math.h>

// HarmonicCQT via f16 MFMA: out[b,t,k] = |sum_n xpad[t*512+n] * (kr[k,n]+i*ki[k,n])|
//
// Path A (ws >= ~10.8MB), 3 dispatches:
//   1. prep_fused : fp32 audio -> padded f16 xp + B-fragment pack (16-bin
//                   chunks, x4096 pre-scale, verified R3-R10 layout) + zero acc
//   2. cqt_mfma7  : async-DMA double-buffered MFMA K-loop (byte-identical to
//                   the verified 47us R9 kernel). 19 balanced K-slices ->
//                   grid (44,19)=836 WGs (~3.3/CU, LDS-limited), guarded
//                   atomic split-K combine. NO end-of-kernel fence/finalize
//                   (R10 showed the device-scope fence serializes WG tails).
//   3. cqt_mag_final : sqrt(re^2+im^2)
// Path B (ws >= ~7.7MB): round-3 LDS-staging MFMA kernel (verified, ~224us).
// Path C: verified fp32 kernel (~370us).
//
// MFMA 16x16x32 layouts (verified rounds 3-10, absmax 4.9e-4):
//   A[m=lane&15][k=(lane>>4)*8+j], B[k=(lane>>4)*8+j][n=lane&15],
//   C/D: col=lane&15, row=(lane>>4)*4+reg.
// bp layout per 16-bin chunk (32 K-cols): 2048B = [64 lanes x 16B re][64 x 16B im]
// global_load_lds: per-lane GLOBAL gather ok; LDS side wave-uniform base,
// lane l lands at base + l*16 (guide m97/m104/m108).

namespace {
constexpr int kSR    = 22050;
constexpr int kHop   = 512;
constexpr int kBins  = 168;
constexpr int kT     = 689;
constexpr int kB     = 4;
constexpr int kS     = 352768;
constexpr float kKScale    = 4096.0f;
constexpr float kKScaleInv = 1.0f / 4096.0f;
constexpr int kG16 = 11;              // 16-bin groups (g10 = bins 160..167)
constexpr int kAcc = kB * kT * kBins * 2;   // unpadded split-K accumulator
// path B layout
constexpr int kTPadB   = 768;
constexpr int kBinPadB = 176;
constexpr int kAccB    = kB * kTPadB * kBinPadB * 2;
}

typedef _Float16 half8 __attribute__((ext_vector_type(8)));
typedef _Float16 half2v __attribute__((ext_vector_type(2)));
typedef float floatx4 __attribute__((ext_vector_type(4)));

struct Jobs {          // path B job table
  int k0[48];
  int lo[48];
  int hi[48];
  int n;
};

struct JobsC {         // path A tables
  int lo16[kG16];      // support start col per 16-bin group (256-aligned)
  int cb16[kG16];      // chunk-prefix per group (bp indexing)
  int mlo[3];          // macro-group (64-bin) support start col
  int sm[24];          // per slice: macro id
  int slo[24];         // per slice: chunk range [slo,shi) rel. to mlo (even)
  int shi[24];
  int ns;
  int totch;
};

__device__ inline void atomAddF(float* p, float v) {
  __hip_atomic_fetch_add(p, v, __ATOMIC_RELAXED, __HIP_MEMORY_SCOPE_AGENT);
}

typedef __attribute__((address_space(3))) unsigned int lds_uint;
typedef __attribute__((address_space(1))) const unsigned int glb_uint;
__device__ __forceinline__ void dma16(const void* g, void* l) {
  __builtin_amdgcn_global_load_lds((glb_uint*)g, (lds_uint*)l, 16, 0, 0);
}

// ---- fused prep: [0,nbx) audio | [nbx,nbx+nbp) bpack | rest zero acc ----
__global__ __launch_bounds__(256) void prep_fused(
    const float* __restrict__ x, const float* __restrict__ kr,
    const float* __restrict__ ki, _Float16* __restrict__ xp,
    _Float16* __restrict__ bp, float* __restrict__ accb,
    const int pad, const int xps, const int nmax,
    const int nbx, const int nbp, const JobsC jt) {
  int bid = blockIdx.x;
  const int tid = threadIdx.x;

  if (bid < nbx) {
    // --- padded f16 audio ---
    const int halfx = xps >> 1;
    const int gid = bid * 256 + tid;
    if (gid >= kB * halfx) return;
    const int b = gid / halfx;
    const int i = (gid - b * halfx) * 2;
    float v0 = 0.f, v1 = 0.f;
    if (i     >= pad && i     < pad + kS) v0 = x[(size_t)b * kS + (i - pad)];
    if (i + 1 >= pad && i + 1 < pad + kS) v1 = x[(size_t)b * kS + (i + 1 - pad)];
    half2v h; h.x = (_Float16)v0; h.y = (_Float16)v1;
    *(half2v*)&xp[(size_t)b * xps + i] = h;
    return;
  }
  bid -= nbx;

  if (bid < nbp) {
    // --- B-fragment pack: 64 threads -> one 16-bin chunk (re+im) ---
    const int chunkid = bid * 4 + (tid >> 6);
    const int lane = tid & 63;
    if (chunkid >= jt.totch) return;
    int g = 0;
    #pragma unroll
    for (int j = 1; j < kG16; ++j)
      if (chunkid >= jt.cb16[j]) g = j;
    const int c = chunkid - jt.cb16[g];
    const int mm = lane & 15;
    const int q  = lane >> 4;
    const int bin  = g * 16 + mm;
    const int col0 = jt.lo16[g] + c * 32 + q * 8;
    const bool binok = (bin < kBins);
    const float* rowr = kr + (size_t)bin * nmax;
    const float* rowi = ki + (size_t)bin * nmax;
    half8 hre, him;
    #pragma unroll
    for (int j = 0; j < 8; ++j) {
      const int col = col0 + j;
      const bool ok = binok && (col < nmax);
      hre[j] = ok ? (_Float16)(rowr[col] * kKScale) : (_Float16)0.f;
      him[j] = ok ? (_Float16)(rowi[col] * kKScale) : (_Float16)0.f;
    }
    _Float16* dst = bp + (size_t)chunkid * 1024 + lane * 8;
    *(half8*)dst = hre;
    *(half8*)(dst + 512) = him;
    return;
  }
  bid -= nbp;

  // --- zero split-K accumulator ---
  const int idx = (bid * 256 + tid) * 4;
  if (idx < kAcc)
    *(floatx4*)&accb[idx] = (floatx4){0.f, 0.f, 0.f, 0.f};
}

// ---- path A main: async-DMA double-buffered MFMA K-loop (verified R9) ----
// LDS per buffer (halfs): A regions [cc(2)][tl(4)] x 512 at 0..4095;
//                         B regions [wave(4)][cc(2)][re/im] x 512 at 4096..12287.
__global__ __launch_bounds__(256) void cqt_mfma7(
    const _Float16* __restrict__ bp, const _Float16* __restrict__ xp,
    float* __restrict__ accb, const int xps, const JobsC jt) {
  __shared__ _Float16 lds[2][12288];   // 2 x 24 KB

  const int sx = blockIdx.y;
  const int fb = blockIdx.x >> 2;      // 0..10
  const int b  = blockIdx.x & 3;
  const int tid  = threadIdx.x;
  const int wave = tid >> 6;
  const int lane = tid & 63;
  const int mm = lane & 15;
  const int q  = lane >> 4;
  const int mac = jt.sm[sx];
  const int g16 = mac * 4 + wave;
  const bool gvalid = (g16 < kG16);
  const int mlo = jt.mlo[mac];
  const int gs = gvalid ? ((jt.lo16[g16] - mlo) >> 5) : 0x7fffffff;
  const int slo = jt.slo[sx];
  const int shi = jt.shi[sx];
  const int fbase = fb * 64;

  // A-DMA source geometry for this wave's 2 staging insts (idx = wave*2+j)
  const _Float16* xb = xp + (size_t)b * xps;
  const int i0 = wave * 2;
  int aoff[2];
  #pragma unroll
  for (int j = 0; j < 2; ++j) {
    const int idx = i0 + j;
    const int tl = idx & 3;
    int row = fbase + tl * 16 + mm;
    if (row > kT - 1) row = kT - 1;
    aoff[j] = row * kHop + q * 8 + ((idx >> 2) * 32);
  }
  const _Float16* bgrp =
      gvalid ? (bp + (size_t)(jt.cb16[g16] - gs) * 1024 + lane * 8) : bp;

  floatx4 accr[4], acci[4];
  #pragma unroll
  for (int tl = 0; tl < 4; ++tl) {
    accr[tl] = (floatx4){0.f, 0.f, 0.f, 0.f};
    acci[tl] = (floatx4){0.f, 0.f, 0.f, 0.f};
  }

  auto stageDMA = [&](int c, int buf) {
    _Float16* L = lds[buf];
    #pragma unroll
    for (int j = 0; j < 2; ++j)
      dma16(xb + mlo + c * 32 + aoff[j], L + (i0 + j) * 512);
    if (gvalid && c >= gs) {
      const _Float16* bs = bgrp + (size_t)c * 1024;
      #pragma unroll
      for (int cc = 0; cc < 2; ++cc)
        #pragma unroll
        for (int ri = 0; ri < 2; ++ri)
          dma16(bs + cc * 1024 + ri * 512,
                L + 4096 + (wave * 4 + cc * 2 + ri) * 512);
    }
  };

  auto compute = [&](int c, int buf) {
    if (!gvalid || c < gs) return;
    const _Float16* L = lds[buf];
    #pragma unroll
    for (int cc = 0; cc < 2; ++cc) {
      const half8 Bre = *(const half8*)(L + 4096 + (wave * 4 + cc * 2) * 512 + lane * 8);
      const half8 Bim = *(const half8*)(L + 4096 + (wave * 4 + cc * 2 + 1) * 512 + lane * 8);
      #pragma unroll
      for (int tl = 0; tl < 4; ++tl) {
        const half8 A = *(const half8*)(L + (cc * 4 + tl) * 512 + lane * 8);
        accr[tl] = __builtin_amdgcn_mfma_f32_16x16x32_f16(A, Bre, accr[tl], 0, 0, 0);
        acci[tl] = __builtin_amdgcn_mfma_f32_16x16x32_f16(A, Bim, acci[tl], 0, 0, 0);
      }
    }
  };

  // 2-barrier double-buffered pipeline (m97 structure, verified R9)
  stageDMA(slo, 0);
  int buf = 0;
  #pragma unroll 1
  for (int c = slo; c < shi; c += 2) {
    __syncthreads();                       // drains this stage's DMA (vmcnt)
    if (c + 2 < shi) stageDMA(c + 2, buf ^ 1);
    compute(c, buf);
    buf ^= 1;
  }

  // epilogue: un-scale + guarded split-K atomic combine (fire-and-forget)
  const int bin = g16 * 16 + mm;
  if (bin < kBins) {
    #pragma unroll
    for (int tl = 0; tl < 4; ++tl) {
      const int tb = fbase + tl * 16 + q * 4;
      #pragma unroll
      for (int r = 0; r < 4; ++r) {
        const int t = tb + r;
        if (t < kT) {
          const size_t o = (((size_t)b * kT + t) * kBins + bin) * 2;
          atomAddF(&accb[o],     accr[tl][r] * kKScaleInv);
          atomAddF(&accb[o + 1], acci[tl][r] * kKScaleInv);
        }
      }
    }
  }
}

// ---- final: magnitude (layout-parametric) ----
__global__ __launch_bounds__(256) void cqt_mag_final(
    const float* __restrict__ accb, float* __restrict__ out,
    const int tp, const int kp) {
  int gid = blockIdx.x * 256 + threadIdx.x;
  if (gid >= kB * kT * kBins) return;
  const int k = gid % kBins;
  const int r = gid / kBins;
  const int t = r % kT;
  const int b = r / kT;
  const float2 v = ((const float2*)accb)[((size_t)b * tp + t) * kp + k];
  out[gid] = sqrtf(v.x * v.x + v.y * v.y);
}

// ================= path B: round-3 LDS-staging MFMA (verified) =============
__global__ __launch_bounds__(256) void prep_x_kernel(
    const float* __restrict__ x, _Float16* __restrict__ xp,
    const int pad, const int xps) {
  const int halfx = xps >> 1;
  int gid = blockIdx.x * 256 + threadIdx.x;
  if (gid >= kB * halfx) return;
  const int b = gid / halfx;
  const int i = (gid - b * halfx) * 2;
  float v0 = 0.f, v1 = 0.f;
  if (i     >= pad && i     < pad + kS) v0 = x[(size_t)b * kS + (i - pad)];
  if (i + 1 >= pad && i + 1 < pad + kS) v1 = x[(size_t)b * kS + (i + 1 - pad)];
  half2v h; h.x = (_Float16)v0; h.y = (_Float16)v1;
  *(half2v*)&xp[(size_t)b * xps + i] = h;
}

__global__ __launch_bounds__(256) void cqt_mfma_kernel(
    const float* __restrict__ kr, const float* __restrict__ ki,
    const _Float16* __restrict__ xp, float* __restrict__ accb,
    const int nmax, const int xps, const Jobs jt) {
  __shared__ _Float16 Bs[2][16][264];
  const int jb = blockIdx.x;
  const int k0   = jt.k0[jb];
  const int n_lo = jt.lo[jb];
  const int n_hi = jt.hi[jb];
  const int b  = blockIdx.z;
  const int fb = blockIdx.y;
  const int tid  = threadIdx.x;
  const int lane = tid & 63;
  const int wave = tid >> 6;
  const int m = lane & 15;
  const int q = lane >> 4;
  const int sbin = tid >> 4;
  const int scol = tid & 15;
  const int gbin = k0 + sbin;
  const bool binok = (gbin < kBins);
  const float* rowr = kr + (size_t)gbin * nmax;
  const float* rowi = ki + (size_t)gbin * nmax;
  const int fbase = fb * 256 + wave * 64;
  const _Float16* ax =
      xp + (size_t)b * xps + (size_t)(fbase + m) * kHop + q * 8;
  floatx4 accr[4], acci[4];
  #pragma unroll
  for (int tl = 0; tl < 4; ++tl) {
    accr[tl] = (floatx4){0.f, 0.f, 0.f, 0.f};
    acci[tl] = (floatx4){0.f, 0.f, 0.f, 0.f};
  }
  for (int n0r = n_lo; n0r < n_hi; n0r += 256) {
    __syncthreads();
    #pragma unroll
    for (int c = 0; c < 16; ++c) {
      const int col = n0r + scol + c * 16;
      const bool ok = binok && (col < nmax);
      const float vr = ok ? rowr[col] : 0.f;
      const float vi = ok ? rowi[col] : 0.f;
      Bs[0][sbin][scol + c * 16] = (_Float16)(vr * kKScale);
      Bs[1][sbin][scol + c * 16] = (_Float16)(vi * kKScale);
    }
    __syncthreads();
    const _Float16* axr = ax + n0r;
    #pragma unroll
    for (int c = 0; c < 8; ++c) {
      const int ko = c * 32 + q * 8;
      const half8 br = *(const half8*)&Bs[0][m][ko];
      const half8 bi = *(const half8*)&Bs[1][m][ko];
      #pragma unroll
      for (int tl = 0; tl < 4; ++tl) {
        const half8 a = *(const half8*)(axr + tl * 16 * kHop + c * 32);
        accr[tl] = __builtin_amdgcn_mfma_f32_16x16x32_f16(a, br, accr[tl], 0, 0, 0);
        acci[tl] = __builtin_amdgcn_mfma_f32_16x16x32_f16(a, bi, acci[tl], 0, 0, 0);
      }
    }
  }
  #pragma unroll
  for (int tl = 0; tl < 4; ++tl) {
    #pragma unroll
    for (int rr = 0; rr < 4; ++rr) {
      const int t = fbase + tl * 16 + q * 4 + rr;
      const size_t o = (((size_t)b * kTPadB + t) * kBinPadB + (k0 + m)) * 2;
      atomAddF(&accb[o],     accr[tl][rr] * kKScaleInv);
      atomAddF(&accb[o + 1], acci[tl][rr] * kKScaleInv);
    }
  }
}

// ================= path C: verified fp32 kernel (round 2) ==================
namespace fb32 {
constexpr int TT = 8;
constexpr int KG = 4;
constexpr int kTTiles  = (kT + TT - 1) / TT;
constexpr int kKGroups = kBins / KG;
constexpr int kWaves   = kB * kTTiles * kKGroups;
}

__global__ __launch_bounds__(256) void cqt_mag_kernel(
    const float* __restrict__ x,
    const float* __restrict__ kr,
    const float* __restrict__ ki,
    float* __restrict__ out,
    const int nmax, const int pad) {
  using namespace fb32;
  const int wave = (blockIdx.x << 2) + (threadIdx.x >> 6);
  const int lane = threadIdx.x & 63;
  if (wave >= kWaves) return;
  const int kg    = wave / (kB * kTTiles);
  const int rem   = wave - kg * (kB * kTTiles);
  const int b     = rem / kTTiles;
  const int ttile = rem - b * kTTiles;
  const int k0 = kg * KG;
  const int t0 = ttile * TT;
  const double Q  = 1.0 / (exp2(1.0 / 24.0) - 1.0);
  const double f0 = 32.7 * exp2((double)k0 / 24.0);
  int N = (int)ceil(Q * (double)kSR / f0) + 8;
  int full_start = nmax - N;
  if (full_start < 0) full_start = 0;
  int tbase[TT], lo[TT], t_last;
  { int t = t0 + TT - 1; if (t > kT - 1) t = kT - 1; t_last = t; }
  #pragma unroll
  for (int tt = 0; tt < TT; ++tt) {
    int t = t0 + tt; if (t > kT - 1) t = kT - 1;
    tbase[tt] = b * kS + t * kHop - pad;
    lo[tt]    = pad - t * kHop;
  }
  int head_start = pad - t_last * kHop;
  if (head_start < full_start) head_start = full_start;
  int safe = pad - t0 * kHop;
  if (safe < head_start) safe = head_start;
  int body_start = nmax - ((nmax - safe) & ~63);
  float accr[TT][KG], acci[TT][KG];
  #pragma unroll
  for (int tt = 0; tt < TT; ++tt)
    #pragma unroll
    for (int kk = 0; kk < KG; ++kk) { accr[tt][kk] = 0.f; acci[tt][kk] = 0.f; }
  for (int n = body_start - 64; n > head_start - 64; n -= 64) {
    const int nn = n + lane;
    const bool kok = (nn >= 0);
    float krv[KG], kiv[KG];
    #pragma unroll
    for (int kk = 0; kk < KG; ++kk) {
      krv[kk] = kok ? kr[(k0 + kk) * nmax + nn] : 0.f;
      kiv[kk] = kok ? ki[(k0 + kk) * nmax + nn] : 0.f;
    }
    float a[TT];
    #pragma unroll
    for (int tt = 0; tt < TT; ++tt)
      a[tt] = (nn >= lo[tt]) ? x[tbase[tt] + nn] : 0.f;
    #pragma unroll
    for (int tt = 0; tt < TT; ++tt)
      #pragma unroll
      for (int kk = 0; kk < KG; ++kk) {
        accr[tt][kk] = fmaf(a[tt], krv[kk], accr[tt][kk]);
        acci[tt][kk] = fmaf(a[tt], kiv[kk], acci[tt][kk]);
      }
  }
  for (int n = body_start; n < nmax; n += 64) {
    const int nn = n + lane;
    float krv[KG], kiv[KG];
    #pragma unroll
    for (int kk = 0; kk < KG; ++kk) {
      krv[kk] = kr[(k0 + kk) * nmax + nn];
      kiv[kk] = ki[(k0 + kk) * nmax + nn];
    }
    float a[TT];
    #pragma unroll
    for (int tt = 0; tt < TT; ++tt)
      a[tt] = x[tbase[tt] + nn];
    #pragma unroll
    for (int tt = 0; tt < TT; ++tt)
      #pragma unroll
      for (int kk = 0; kk < KG; ++kk) {
        accr[tt][kk] = fmaf(a[tt], krv[kk], accr[tt][kk]);
        acci[tt][kk] = fmaf(a[tt], kiv[kk], acci[tt][kk]);
      }
  }
  #pragma unroll
  for (int tt = 0; tt < TT; ++tt) {
    #pragma unroll
    for (int kk = 0; kk < KG; ++kk) {
      float r = accr[tt][kk];
      float i = acci[tt][kk];
      #pragma unroll
      for (int s = 32; s > 0; s >>= 1) {
        r += __shfl_xor(r, s, 64);
        i += __shfl_xor(i, s, 64);
      }
      if (lane == 0) {
        const int t = t0 + tt;
        if (t < kT)
          out[(b * kT + t) * kBins + (k0 + kk)] = sqrtf(r * r + i * i);
      }
    }
  }
}
// ============================================================================

extern "C" void kernel_launch(void* const* d_in, const int* in_sizes, int n_in,
                              void* d_out, int out_size, void* d_ws, size_t ws_size,
                              hipStream_t stream) {
  const float* x  = (const float*)d_in[0];   // [4, 1, 352768]
  const float* kr = (const float*)d_in[1];   // [168, nmax]
  const float* ki = (const float*)d_in[2];   // [168, nmax]
  float* out = (float*)d_out;                // [4, 1, 689, 168]

  const int nmax = in_sizes[1] / kBins;      // 23013 (runtime truth)
  const int pad  = nmax - kHop;

  const int kcap = ((nmax + 255) / 256) * 256;   // 23040
  const double Q = 1.0 / (exp2(1.0 / 24.0) - 1.0);

  // ---- path A tables ----
  JobsC jc;
  int tot = 0;
  for (int g = 0; g < kG16; ++g) {
    const double f0 = 32.7 * exp2((double)(16 * g) / 24.0);
    const int N = (int)ceil(Q * (double)kSR / f0) + 8;
    int lo = nmax - N;
    if (lo < 0) lo = 0;
    lo &= ~255;
    jc.lo16[g] = lo;
    jc.cb16[g] = tot;
    tot += (kcap - lo) / 32;
  }
  jc.totch = tot;                        // ~1980 chunks
  const int nsl_m[3] = {15, 3, 1};       // ~48/40/24-chunk slices -> ns=19
  int ns = 0;
  for (int m = 0; m < 3; ++m) {
    jc.mlo[m] = jc.lo16[4 * m];
    const int C = (kcap - jc.mlo[m]) / 32;       // 720 / 120 / 24
    const int nsl = nsl_m[m];
    const int len = ((C + nsl - 1) / nsl + 1) & ~1;
    for (int s = 0; s < nsl && ns < 24; ++s) {
      const int lo = s * len;
      if (lo >= C) break;
      int hi = lo + len;
      if (hi > C) hi = C;
      jc.sm[ns] = m; jc.slo[ns] = lo; jc.shi[ns] = hi;
      ++ns;
    }
  }
  jc.ns = ns;                            // 19 expected

  // ---- path A ws layout ----
  const int xpsA = (kT - 1) * kHop + kcap + 256;           // 375,552
  const size_t xpA_bytes = (size_t)kB * xpsA * sizeof(_Float16);
  const size_t accA_off  = (xpA_bytes + 511) & ~(size_t)511;
  const size_t accA_bytes = (size_t)kAcc * sizeof(float);
  const size_t bpA_off   = (accA_off + accA_bytes + 511) & ~(size_t)511;
  const size_t bpA_bytes = (size_t)tot * 2048;
  const size_t ws_A = bpA_off + bpA_bytes;                 // ~10.8 MB

  // ---- path B layout ----
  const int xpsB = (kTPadB - 1) * kHop + kcap + 256;
  const size_t xpB_bytes = (size_t)kB * xpsB * sizeof(_Float16);
  const size_t accB_off  = (xpB_bytes + 511) & ~(size_t)511;
  const size_t accB_bytes = (size_t)kAccB * sizeof(float);
  const size_t ws_B = accB_off + accB_bytes;

  if (ws_size >= ws_A) {
    // ---- path A: 3 dispatches ----
    _Float16* xp = (_Float16*)d_ws;
    float* accb  = (float*)((char*)d_ws + accA_off);
    _Float16* bp = (_Float16*)((char*)d_ws + bpA_off);

    const int nbx = (kB * (xpsA / 2) + 255) / 256;   // audio blocks
    const int nbp = (tot + 3) / 4;                   // bpack blocks (4 chunks ea)
    const int nba = (kAcc / 4 + 255) / 256;          // acc-zero blocks
    prep_fused<<<nbx + nbp + nba, 256, 0, stream>>>(
        x, kr, ki, xp, bp, accb, pad, xpsA, nmax, nbx, nbp, jc);

    {
      dim3 grid(44, ns);   // x = fb(11) * b(4); y = balanced K-slices
      cqt_mfma7<<<grid, 256, 0, stream>>>(bp, xp, accb, xpsA, jc);
    }
    {
      const int total = kB * kT * kBins;
      cqt_mag_final<<<(total + 255) / 256, 256, 0, stream>>>(
          accb, out, kT, kBins);
    }
    return;
  }

  if (ws_size >= ws_B) {
    // ---- path B (round-3, verified ~224us) ----
    _Float16* xp = (_Float16*)d_ws;
    float* accb  = (float*)((char*)d_ws + accB_off);
    Jobs jt;
    int nj = 0;
    for (int g = 0; g < 11; ++g) {
      const int gk0 = 16 * g;
      const double f0 = 32.7 * exp2((double)gk0 / 24.0);
      const int N = (int)ceil(Q * (double)kSR / f0) + 8;
      int lo = nmax - N;
      if (lo < 0) lo = 0;
      lo = (lo / 2048) * 2048;
      for (int s = lo; s < kcap && nj < 48; s += 2048) {
        jt.k0[nj] = gk0;
        jt.lo[nj] = s;
        jt.hi[nj] = (s + 2048 < kcap) ? s + 2048 : kcap;
        ++nj;
      }
    }
    jt.n = nj;
    hipMemsetAsync(accb, 0, accB_bytes, stream);
    {
      const int total = kB * (xpsB / 2);
      prep_x_kernel<<<(total + 255) / 256, 256, 0, stream>>>(x, xp, pad, xpsB);
    }
    {
      dim3 grid(nj, kTPadB / 256, kB);
      cqt_mfma_kernel<<<grid, 256, 0, stream>>>(kr, ki, xp, accb, nmax, xpsB, jt);
    }
    {
      const int total = kB * kT * kBins;
      cqt_mag_final<<<(total + 255) / 256, 256, 0, stream>>>(
          accb, out, kTPadB, kBinPadB);
    }
    return;
  }

  // ---- path C: fp32 fallback ----
  {
    const int blocks = fb32::kWaves / 4;
    cqt_mag_kernel<<<blocks, 256, 0, stream>>>(x, kr, ki, out, nmax, pad);
  }
}

// Round 12
// 128.825 us; speedup vs baseline: 1.6538x; 1.1831x over previous
//
#include <hip/hip_runtime.h>
#include <math.h>

// HarmonicCQT via f16 MFMA: out[b,t,k] = |sum_n xpad[t*512+n] * (kr[k,n]+i*ki[k,n])|
//
// Path A (ws >= ~10.8MB), 3 dispatches:
//   1. prep_fused : fp32 audio -> padded f16 xp (8 elems/thread, 16B stores)
//                   + B-fragment pack (verified R3-R11 layout) + zero acc
//   2. cqt_mfma7  : async-DMA double-buffered MFMA K-loop, ns=11 balanced
//                   K-slices (R9-verified optimum: 484 WGs, main 47us).
//                   Fire-and-forget guarded atomic split-K; NO fences.
//   3. cqt_mag_final : sqrt(re^2+im^2), 4 outputs/thread (float4 I/O)
// Path B (ws >= ~7.7MB): round-3 LDS-staging MFMA kernel (verified, ~224us).
// Path C: verified fp32 kernel (~370us).
//
// Measured cost curve (mains): ns=11 -> 47us (R9), ns=19 -> 72us (R11),
// ns=19+fence -> 139us (R10). Split-K atomic volume, not occupancy, is the
// binding constraint; ns=11 is the optimum.
//
// MFMA 16x16x32 layouts (verified rounds 3-11, absmax 4.9e-4):
//   A[m=lane&15][k=(lane>>4)*8+j], B[k=(lane>>4)*8+j][n=lane&15],
//   C/D: col=lane&15, row=(lane>>4)*4+reg.
// bp layout per 16-bin chunk (32 K-cols): 2048B = [64 lanes x 16B re][64 x 16B im]
// global_load_lds: per-lane GLOBAL gather ok; LDS side wave-uniform base,
// lane l lands at base + l*16 (guide m97/m104/m108).

namespace {
constexpr int kSR    = 22050;
constexpr int kHop   = 512;
constexpr int kBins  = 168;
constexpr int kT     = 689;
constexpr int kB     = 4;
constexpr int kS     = 352768;
constexpr float kKScale    = 4096.0f;
constexpr float kKScaleInv = 1.0f / 4096.0f;
constexpr int kG16 = 11;              // 16-bin groups (g10 = bins 160..167)
constexpr int kAcc = kB * kT * kBins * 2;   // unpadded split-K accumulator
// path B layout
constexpr int kTPadB   = 768;
constexpr int kBinPadB = 176;
constexpr int kAccB    = kB * kTPadB * kBinPadB * 2;
}

typedef _Float16 half8 __attribute__((ext_vector_type(8)));
typedef _Float16 half2v __attribute__((ext_vector_type(2)));
typedef float floatx4 __attribute__((ext_vector_type(4)));

struct Jobs {          // path B job table
  int k0[48];
  int lo[48];
  int hi[48];
  int n;
};

struct JobsC {         // path A tables
  int lo16[kG16];      // support start col per 16-bin group (256-aligned)
  int cb16[kG16];      // chunk-prefix per group (bp indexing)
  int mlo[3];          // macro-group (64-bin) support start col
  int sm[24];          // per slice: macro id
  int slo[24];         // per slice: chunk range [slo,shi) rel. to mlo (even)
  int shi[24];
  int ns;
  int totch;
};

__device__ inline void atomAddF(float* p, float v) {
  __hip_atomic_fetch_add(p, v, __ATOMIC_RELAXED, __HIP_MEMORY_SCOPE_AGENT);
}

typedef __attribute__((address_space(3))) unsigned int lds_uint;
typedef __attribute__((address_space(1))) const unsigned int glb_uint;
__device__ __forceinline__ void dma16(const void* g, void* l) {
  __builtin_amdgcn_global_load_lds((glb_uint*)g, (lds_uint*)l, 16, 0, 0);
}

// ---- fused prep: [0,nbx) audio | [nbx,nbx+nbp) bpack | rest zero acc ----
__global__ __launch_bounds__(256) void prep_fused(
    const float* __restrict__ x, const float* __restrict__ kr,
    const float* __restrict__ ki, _Float16* __restrict__ xp,
    _Float16* __restrict__ bp, float* __restrict__ accb,
    const int pad, const int xps, const int nmax,
    const int nbx, const int nbp, const JobsC jt) {
  int bid = blockIdx.x;
  const int tid = threadIdx.x;

  if (bid < nbx) {
    // --- padded f16 audio: 8 elements/thread, one 16B store ---
    const int octx = xps >> 3;
    const int gid = bid * 256 + tid;
    if (gid >= kB * octx) return;
    const int b = gid / octx;
    const int i = (gid - b * octx) * 8;
    const float* xb = x + (size_t)b * kS - pad;
    half8 h;
    #pragma unroll
    for (int j = 0; j < 8; ++j) {
      const int e = i + j;
      h[j] = (e >= pad && e < pad + kS) ? (_Float16)xb[e] : (_Float16)0.f;
    }
    *(half8*)&xp[(size_t)b * xps + i] = h;
    return;
  }
  bid -= nbx;

  if (bid < nbp) {
    // --- B-fragment pack: 64 threads -> one 16-bin chunk (re+im) ---
    const int chunkid = bid * 4 + (tid >> 6);
    const int lane = tid & 63;
    if (chunkid >= jt.totch) return;
    int g = 0;
    #pragma unroll
    for (int j = 1; j < kG16; ++j)
      if (chunkid >= jt.cb16[j]) g = j;
    const int c = chunkid - jt.cb16[g];
    const int mm = lane & 15;
    const int q  = lane >> 4;
    const int bin  = g * 16 + mm;
    const int col0 = jt.lo16[g] + c * 32 + q * 8;
    const bool binok = (bin < kBins);
    const float* rowr = kr + (size_t)bin * nmax;
    const float* rowi = ki + (size_t)bin * nmax;
    half8 hre, him;
    #pragma unroll
    for (int j = 0; j < 8; ++j) {
      const int col = col0 + j;
      const bool ok = binok && (col < nmax);
      hre[j] = ok ? (_Float16)(rowr[col] * kKScale) : (_Float16)0.f;
      him[j] = ok ? (_Float16)(rowi[col] * kKScale) : (_Float16)0.f;
    }
    _Float16* dst = bp + (size_t)chunkid * 1024 + lane * 8;
    *(half8*)dst = hre;
    *(half8*)(dst + 512) = him;
    return;
  }
  bid -= nbp;

  // --- zero split-K accumulator ---
  const int idx = (bid * 256 + tid) * 4;
  if (idx < kAcc)
    *(floatx4*)&accb[idx] = (floatx4){0.f, 0.f, 0.f, 0.f};
}

// ---- path A main: async-DMA double-buffered MFMA K-loop (verified R9) ----
// LDS per buffer (halfs): A regions [cc(2)][tl(4)] x 512 at 0..4095;
//                         B regions [wave(4)][cc(2)][re/im] x 512 at 4096..12287.
__global__ __launch_bounds__(256) void cqt_mfma7(
    const _Float16* __restrict__ bp, const _Float16* __restrict__ xp,
    float* __restrict__ accb, const int xps, const JobsC jt) {
  __shared__ _Float16 lds[2][12288];   // 2 x 24 KB

  const int sx = blockIdx.y;
  const int fb = blockIdx.x >> 2;      // 0..10
  const int b  = blockIdx.x & 3;
  const int tid  = threadIdx.x;
  const int wave = tid >> 6;
  const int lane = tid & 63;
  const int mm = lane & 15;
  const int q  = lane >> 4;
  const int mac = jt.sm[sx];
  const int g16 = mac * 4 + wave;
  const bool gvalid = (g16 < kG16);
  const int mlo = jt.mlo[mac];
  const int gs = gvalid ? ((jt.lo16[g16] - mlo) >> 5) : 0x7fffffff;
  const int slo = jt.slo[sx];
  const int shi = jt.shi[sx];
  const int fbase = fb * 64;

  // A-DMA source geometry for this wave's 2 staging insts (idx = wave*2+j)
  const _Float16* xb = xp + (size_t)b * xps;
  const int i0 = wave * 2;
  int aoff[2];
  #pragma unroll
  for (int j = 0; j < 2; ++j) {
    const int idx = i0 + j;
    const int tl = idx & 3;
    int row = fbase + tl * 16 + mm;
    if (row > kT - 1) row = kT - 1;
    aoff[j] = row * kHop + q * 8 + ((idx >> 2) * 32);
  }
  const _Float16* bgrp =
      gvalid ? (bp + (size_t)(jt.cb16[g16] - gs) * 1024 + lane * 8) : bp;

  floatx4 accr[4], acci[4];
  #pragma unroll
  for (int tl = 0; tl < 4; ++tl) {
    accr[tl] = (floatx4){0.f, 0.f, 0.f, 0.f};
    acci[tl] = (floatx4){0.f, 0.f, 0.f, 0.f};
  }

  auto stageDMA = [&](int c, int buf) {
    _Float16* L = lds[buf];
    #pragma unroll
    for (int j = 0; j < 2; ++j)
      dma16(xb + mlo + c * 32 + aoff[j], L + (i0 + j) * 512);
    if (gvalid && c >= gs) {
      const _Float16* bs = bgrp + (size_t)c * 1024;
      #pragma unroll
      for (int cc = 0; cc < 2; ++cc)
        #pragma unroll
        for (int ri = 0; ri < 2; ++ri)
          dma16(bs + cc * 1024 + ri * 512,
                L + 4096 + (wave * 4 + cc * 2 + ri) * 512);
    }
  };

  auto compute = [&](int c, int buf) {
    if (!gvalid || c < gs) return;
    const _Float16* L = lds[buf];
    #pragma unroll
    for (int cc = 0; cc < 2; ++cc) {
      const half8 Bre = *(const half8*)(L + 4096 + (wave * 4 + cc * 2) * 512 + lane * 8);
      const half8 Bim = *(const half8*)(L + 4096 + (wave * 4 + cc * 2 + 1) * 512 + lane * 8);
      #pragma unroll
      for (int tl = 0; tl < 4; ++tl) {
        const half8 A = *(const half8*)(L + (cc * 4 + tl) * 512 + lane * 8);
        accr[tl] = __builtin_amdgcn_mfma_f32_16x16x32_f16(A, Bre, accr[tl], 0, 0, 0);
        acci[tl] = __builtin_amdgcn_mfma_f32_16x16x32_f16(A, Bim, acci[tl], 0, 0, 0);
      }
    }
  };

  // 2-barrier double-buffered pipeline (m97 structure, verified R9)
  stageDMA(slo, 0);
  int buf = 0;
  #pragma unroll 1
  for (int c = slo; c < shi; c += 2) {
    __syncthreads();                       // drains this stage's DMA (vmcnt)
    if (c + 2 < shi) stageDMA(c + 2, buf ^ 1);
    compute(c, buf);
    buf ^= 1;
  }

  // epilogue: un-scale + guarded split-K atomic combine (fire-and-forget)
  const int bin = g16 * 16 + mm;
  if (bin < kBins) {
    #pragma unroll
    for (int tl = 0; tl < 4; ++tl) {
      const int tb = fbase + tl * 16 + q * 4;
      #pragma unroll
      for (int r = 0; r < 4; ++r) {
        const int t = tb + r;
        if (t < kT) {
          const size_t o = (((size_t)b * kT + t) * kBins + bin) * 2;
          atomAddF(&accb[o],     accr[tl][r] * kKScaleInv);
          atomAddF(&accb[o + 1], acci[tl][r] * kKScaleInv);
        }
      }
    }
  }
}

// ---- final: magnitude, 4 outputs/thread (path A tight layout) ----
__global__ __launch_bounds__(256) void cqt_mag4(
    const float* __restrict__ accb, float* __restrict__ out) {
  const int gid = (blockIdx.x * 256 + threadIdx.x) * 4;
  if (gid >= kB * kT * kBins) return;
  const floatx4 v0 = *(const floatx4*)&accb[gid * 2];
  const floatx4 v1 = *(const floatx4*)&accb[gid * 2 + 4];
  floatx4 o;
  o[0] = sqrtf(v0[0] * v0[0] + v0[1] * v0[1]);
  o[1] = sqrtf(v0[2] * v0[2] + v0[3] * v0[3]);
  o[2] = sqrtf(v1[0] * v1[0] + v1[1] * v1[1]);
  o[3] = sqrtf(v1[2] * v1[2] + v1[3] * v1[3]);
  *(floatx4*)&out[gid] = o;
}

// ---- final: magnitude (layout-parametric, path B) ----
__global__ __launch_bounds__(256) void cqt_mag_final(
    const float* __restrict__ accb, float* __restrict__ out,
    const int tp, const int kp) {
  int gid = blockIdx.x * 256 + threadIdx.x;
  if (gid >= kB * kT * kBins) return;
  const int k = gid % kBins;
  const int r = gid / kBins;
  const int t = r % kT;
  const int b = r / kT;
  const float2 v = ((const float2*)accb)[((size_t)b * tp + t) * kp + k];
  out[gid] = sqrtf(v.x * v.x + v.y * v.y);
}

// ================= path B: round-3 LDS-staging MFMA (verified) =============
__global__ __launch_bounds__(256) void prep_x_kernel(
    const float* __restrict__ x, _Float16* __restrict__ xp,
    const int pad, const int xps) {
  const int halfx = xps >> 1;
  int gid = blockIdx.x * 256 + threadIdx.x;
  if (gid >= kB * halfx) return;
  const int b = gid / halfx;
  const int i = (gid - b * halfx) * 2;
  float v0 = 0.f, v1 = 0.f;
  if (i     >= pad && i     < pad + kS) v0 = x[(size_t)b * kS + (i - pad)];
  if (i + 1 >= pad && i + 1 < pad + kS) v1 = x[(size_t)b * kS + (i + 1 - pad)];
  half2v h; h.x = (_Float16)v0; h.y = (_Float16)v1;
  *(half2v*)&xp[(size_t)b * xps + i] = h;
}

__global__ __launch_bounds__(256) void cqt_mfma_kernel(
    const float* __restrict__ kr, const float* __restrict__ ki,
    const _Float16* __restrict__ xp, float* __restrict__ accb,
    const int nmax, const int xps, const Jobs jt) {
  __shared__ _Float16 Bs[2][16][264];
  const int jb = blockIdx.x;
  const int k0   = jt.k0[jb];
  const int n_lo = jt.lo[jb];
  const int n_hi = jt.hi[jb];
  const int b  = blockIdx.z;
  const int fb = blockIdx.y;
  const int tid  = threadIdx.x;
  const int lane = tid & 63;
  const int wave = tid >> 6;
  const int m = lane & 15;
  const int q = lane >> 4;
  const int sbin = tid >> 4;
  const int scol = tid & 15;
  const int gbin = k0 + sbin;
  const bool binok = (gbin < kBins);
  const float* rowr = kr + (size_t)gbin * nmax;
  const float* rowi = ki + (size_t)gbin * nmax;
  const int fbase = fb * 256 + wave * 64;
  const _Float16* ax =
      xp + (size_t)b * xps + (size_t)(fbase + m) * kHop + q * 8;
  floatx4 accr[4], acci[4];
  #pragma unroll
  for (int tl = 0; tl < 4; ++tl) {
    accr[tl] = (floatx4){0.f, 0.f, 0.f, 0.f};
    acci[tl] = (floatx4){0.f, 0.f, 0.f, 0.f};
  }
  for (int n0r = n_lo; n0r < n_hi; n0r += 256) {
    __syncthreads();
    #pragma unroll
    for (int c = 0; c < 16; ++c) {
      const int col = n0r + scol + c * 16;
      const bool ok = binok && (col < nmax);
      const float vr = ok ? rowr[col] : 0.f;
      const float vi = ok ? rowi[col] : 0.f;
      Bs[0][sbin][scol + c * 16] = (_Float16)(vr * kKScale);
      Bs[1][sbin][scol + c * 16] = (_Float16)(vi * kKScale);
    }
    __syncthreads();
    const _Float16* axr = ax + n0r;
    #pragma unroll
    for (int c = 0; c < 8; ++c) {
      const int ko = c * 32 + q * 8;
      const half8 br = *(const half8*)&Bs[0][m][ko];
      const half8 bi = *(const half8*)&Bs[1][m][ko];
      #pragma unroll
      for (int tl = 0; tl < 4; ++tl) {
        const half8 a = *(const half8*)(axr + tl * 16 * kHop + c * 32);
        accr[tl] = __builtin_amdgcn_mfma_f32_16x16x32_f16(a, br, accr[tl], 0, 0, 0);
        acci[tl] = __builtin_amdgcn_mfma_f32_16x16x32_f16(a, bi, acci[tl], 0, 0, 0);
      }
    }
  }
  #pragma unroll
  for (int tl = 0; tl < 4; ++tl) {
    #pragma unroll
    for (int rr = 0; rr < 4; ++rr) {
      const int t = fbase + tl * 16 + q * 4 + rr;
      const size_t o = (((size_t)b * kTPadB + t) * kBinPadB + (k0 + m)) * 2;
      atomAddF(&accb[o],     accr[tl][rr] * kKScaleInv);
      atomAddF(&accb[o + 1], acci[tl][rr] * kKScaleInv);
    }
  }
}

// ================= path C: verified fp32 kernel (round 2) ==================
namespace fb32 {
constexpr int TT = 8;
constexpr int KG = 4;
constexpr int kTTiles  = (kT + TT - 1) / TT;
constexpr int kKGroups = kBins / KG;
constexpr int kWaves   = kB * kTTiles * kKGroups;
}

__global__ __launch_bounds__(256) void cqt_mag_kernel(
    const float* __restrict__ x,
    const float* __restrict__ kr,
    const float* __restrict__ ki,
    float* __restrict__ out,
    const int nmax, const int pad) {
  using namespace fb32;
  const int wave = (blockIdx.x << 2) + (threadIdx.x >> 6);
  const int lane = threadIdx.x & 63;
  if (wave >= kWaves) return;
  const int kg    = wave / (kB * kTTiles);
  const int rem   = wave - kg * (kB * kTTiles);
  const int b     = rem / kTTiles;
  const int ttile = rem - b * kTTiles;
  const int k0 = kg * KG;
  const int t0 = ttile * TT;
  const double Q  = 1.0 / (exp2(1.0 / 24.0) - 1.0);
  const double f0 = 32.7 * exp2((double)k0 / 24.0);
  int N = (int)ceil(Q * (double)kSR / f0) + 8;
  int full_start = nmax - N;
  if (full_start < 0) full_start = 0;
  int tbase[TT], lo[TT], t_last;
  { int t = t0 + TT - 1; if (t > kT - 1) t = kT - 1; t_last = t; }
  #pragma unroll
  for (int tt = 0; tt < TT; ++tt) {
    int t = t0 + tt; if (t > kT - 1) t = kT - 1;
    tbase[tt] = b * kS + t * kHop - pad;
    lo[tt]    = pad - t * kHop;
  }
  int head_start = pad - t_last * kHop;
  if (head_start < full_start) head_start = full_start;
  int safe = pad - t0 * kHop;
  if (safe < head_start) safe = head_start;
  int body_start = nmax - ((nmax - safe) & ~63);
  float accr[TT][KG], acci[TT][KG];
  #pragma unroll
  for (int tt = 0; tt < TT; ++tt)
    #pragma unroll
    for (int kk = 0; kk < KG; ++kk) { accr[tt][kk] = 0.f; acci[tt][kk] = 0.f; }
  for (int n = body_start - 64; n > head_start - 64; n -= 64) {
    const int nn = n + lane;
    const bool kok = (nn >= 0);
    float krv[KG], kiv[KG];
    #pragma unroll
    for (int kk = 0; kk < KG; ++kk) {
      krv[kk] = kok ? kr[(k0 + kk) * nmax + nn] : 0.f;
      kiv[kk] = kok ? ki[(k0 + kk) * nmax + nn] : 0.f;
    }
    float a[TT];
    #pragma unroll
    for (int tt = 0; tt < TT; ++tt)
      a[tt] = (nn >= lo[tt]) ? x[tbase[tt] + nn] : 0.f;
    #pragma unroll
    for (int tt = 0; tt < TT; ++tt)
      #pragma unroll
      for (int kk = 0; kk < KG; ++kk) {
        accr[tt][kk] = fmaf(a[tt], krv[kk], accr[tt][kk]);
        acci[tt][kk] = fmaf(a[tt], kiv[kk], acci[tt][kk]);
      }
  }
  for (int n = body_start; n < nmax; n += 64) {
    const int nn = n + lane;
    float krv[KG], kiv[KG];
    #pragma unroll
    for (int kk = 0; kk < KG; ++kk) {
      krv[kk] = kr[(k0 + kk) * nmax + nn];
      kiv[kk] = ki[(k0 + kk) * nmax + nn];
    }
    float a[TT];
    #pragma unroll
    for (int tt = 0; tt < TT; ++tt)
      a[tt] = x[tbase[tt] + nn];
    #pragma unroll
    for (int tt = 0; tt < TT; ++tt)
      #pragma unroll
      for (int kk = 0; kk < KG; ++kk) {
        accr[tt][kk] = fmaf(a[tt], krv[kk], accr[tt][kk]);
        acci[tt][kk] = fmaf(a[tt], kiv[kk], acci[tt][kk]);
      }
  }
  #pragma unroll
  for (int tt = 0; tt < TT; ++tt) {
    #pragma unroll
    for (int kk = 0; kk < KG; ++kk) {
      float r = accr[tt][kk];
      float i = acci[tt][kk];
      #pragma unroll
      for (int s = 32; s > 0; s >>= 1) {
        r += __shfl_xor(r, s, 64);
        i += __shfl_xor(i, s, 64);
      }
      if (lane == 0) {
        const int t = t0 + tt;
        if (t < kT)
          out[(b * kT + t) * kBins + (k0 + kk)] = sqrtf(r * r + i * i);
      }
    }
  }
}
// ============================================================================

extern "C" void kernel_launch(void* const* d_in, const int* in_sizes, int n_in,
                              void* d_out, int out_size, void* d_ws, size_t ws_size,
                              hipStream_t stream) {
  const float* x  = (const float*)d_in[0];   // [4, 1, 352768]
  const float* kr = (const float*)d_in[1];   // [168, nmax]
  const float* ki = (const float*)d_in[2];   // [168, nmax]
  float* out = (float*)d_out;                // [4, 1, 689, 168]

  const int nmax = in_sizes[1] / kBins;      // 23013 (runtime truth)
  const int pad  = nmax - kHop;

  const int kcap = ((nmax + 255) / 256) * 256;   // 23040
  const double Q = 1.0 / (exp2(1.0 / 24.0) - 1.0);

  // ---- path A tables ----
  JobsC jc;
  int tot = 0;
  for (int g = 0; g < kG16; ++g) {
    const double f0 = 32.7 * exp2((double)(16 * g) / 24.0);
    const int N = (int)ceil(Q * (double)kSR / f0) + 8;
    int lo = nmax - N;
    if (lo < 0) lo = 0;
    lo &= ~255;
    jc.lo16[g] = lo;
    jc.cb16[g] = tot;
    tot += (kcap - lo) / 32;
  }
  jc.totch = tot;                        // ~1980 chunks
  // ns=11 slice table (R9-verified optimum: 8/2/1 slices, <=96 chunks each)
  int ns = 0;
  for (int m = 0; m < 3; ++m) {
    jc.mlo[m] = jc.lo16[4 * m];
    const int C = (kcap - jc.mlo[m]) / 32;       // 720 / 120 / 24
    const int nsl = (C + 95) / 96;               // 8 / 2 / 1
    const int len = ((C + nsl - 1) / nsl + 1) & ~1;
    for (int s = 0; s < nsl && ns < 24; ++s) {
      const int lo = s * len;
      if (lo >= C) break;
      int hi = lo + len;
      if (hi > C) hi = C;
      jc.sm[ns] = m; jc.slo[ns] = lo; jc.shi[ns] = hi;
      ++ns;
    }
  }
  jc.ns = ns;                            // 11 expected

  // ---- path A ws layout ----
  const int xpsA = (kT - 1) * kHop + kcap + 256;           // 375,552 (%8==0)
  const size_t xpA_bytes = (size_t)kB * xpsA * sizeof(_Float16);
  const size_t accA_off  = (xpA_bytes + 511) & ~(size_t)511;
  const size_t accA_bytes = (size_t)kAcc * sizeof(float);
  const size_t bpA_off   = (accA_off + accA_bytes + 511) & ~(size_t)511;
  const size_t bpA_bytes = (size_t)tot * 2048;
  const size_t ws_A = bpA_off + bpA_bytes;                 // ~10.8 MB

  // ---- path B layout ----
  const int xpsB = (kTPadB - 1) * kHop + kcap + 256;
  const size_t xpB_bytes = (size_t)kB * xpsB * sizeof(_Float16);
  const size_t accB_off  = (xpB_bytes + 511) & ~(size_t)511;
  const size_t accB_bytes = (size_t)kAccB * sizeof(float);
  const size_t ws_B = accB_off + accB_bytes;

  if (ws_size >= ws_A) {
    // ---- path A: 3 dispatches ----
    _Float16* xp = (_Float16*)d_ws;
    float* accb  = (float*)((char*)d_ws + accA_off);
    _Float16* bp = (_Float16*)((char*)d_ws + bpA_off);

    const int nbx = (kB * (xpsA / 8) + 255) / 256;   // audio blocks (8 el/thr)
    const int nbp = (tot + 3) / 4;                   // bpack blocks (4 chunks ea)
    const int nba = (kAcc / 4 + 255) / 256;          // acc-zero blocks
    prep_fused<<<nbx + nbp + nba, 256, 0, stream>>>(
        x, kr, ki, xp, bp, accb, pad, xpsA, nmax, nbx, nbp, jc);

    {
      dim3 grid(44, ns);   // x = fb(11) * b(4); y = balanced K-slices (ns=11)
      cqt_mfma7<<<grid, 256, 0, stream>>>(bp, xp, accb, xpsA, jc);
    }
    {
      const int total = kB * kT * kBins;       // 463,008 (% 4 == 0)
      cqt_mag4<<<(total / 4 + 255) / 256, 256, 0, stream>>>(accb, out);
    }
    return;
  }

  if (ws_size >= ws_B) {
    // ---- path B (round-3, verified ~224us) ----
    _Float16* xp = (_Float16*)d_ws;
    float* accb  = (float*)((char*)d_ws + accB_off);
    Jobs jt;
    int nj = 0;
    for (int g = 0; g < 11; ++g) {
      const int gk0 = 16 * g;
      const double f0 = 32.7 * exp2((double)gk0 / 24.0);
      const int N = (int)ceil(Q * (double)kSR / f0) + 8;
      int lo = nmax - N;
      if (lo < 0) lo = 0;
      lo = (lo / 2048) * 2048;
      for (int s = lo; s < kcap && nj < 48; s += 2048) {
        jt.k0[nj] = gk0;
        jt.lo[nj] = s;
        jt.hi[nj] = (s + 2048 < kcap) ? s + 2048 : kcap;
        ++nj;
      }
    }
    jt.n = nj;
    hipMemsetAsync(accb, 0, accB_bytes, stream);
    {
      const int total = kB * (xpsB / 2);
      prep_x_kernel<<<(total + 255) / 256, 256, 0, stream>>>(x, xp, pad, xpsB);
    }
    {
      dim3 grid(nj, kTPadB / 256, kB);
      cqt_mfma_kernel<<<grid, 256, 0, stream>>>(kr, ki, xp, accb, nmax, xpsB, jt);
    }
    {
      const int total = kB * kT * kBins;
      cqt_mag_final<<<(total + 255) / 256, 256, 0, stream>>>(
          accb, out, kTPadB, kBinPadB);
    }
    return;
  }

  // ---- path C: fp32 fallback ----
  {
    const int blocks = fb32::kWaves / 4;
    cqt_mag_kernel<<<blocks, 256, 0, stream>>>(x, kr, ki, out, nmax, pad);
  }
}

// Round 13
// 128.431 us; speedup vs baseline: 1.6589x; 1.0031x over previous
//
#include <hip/hip_runtime.h>
#include <math.h>

// HarmonicCQT via f16 MFMA: out[b,t,k] = |sum_n xpad[t*512+n] * (kr[k,n]+i*ki[k,n])|
//
// Path A (ws >= ~10.8MB), 3 dispatches:
//   1. prep_fused : fp32 audio -> padded f16 xp (8 elems/thread, 16B stores)
//                   + B-fragment pack (verified R3-R12 layout) + zero acc
//   2. cqt_mfma9  : async-DMA double-buffered MFMA K-loop; 32-frame x 64-bin
//                   WGs (4 waves x [32 frames x 16 bins]) -> 968 WGs (~3.8/CU)
//                   with IDENTICAL total atomic count to R12's 484-WG config
//                   (frame-split adds TLP, not atomics). ns=11 K-slices
//                   (R9/R12-verified optimum). Fire-and-forget guarded
//                   atomic split-K; NO fences.
//   3. cqt_mag4   : sqrt(re^2+im^2), 4 outputs/thread (float4 I/O)
// Path B (ws >= ~7.7MB): round-3 LDS-staging MFMA kernel (verified, ~224us).
// Path C: verified fp32 kernel (~370us).
//
// Measured cost curve (mains): ns=11/64-frame -> 47-48us (R9/R12),
// ns=19 -> 72us (R11), ns=19+fence -> 139us (R10). Split-K atomic volume is
// the binding constraint; this round holds it constant while doubling WGs.
//
// MFMA 16x16x32 layouts (verified rounds 3-12, absmax 4.9e-4):
//   A[m=lane&15][k=(lane>>4)*8+j], B[k=(lane>>4)*8+j][n=lane&15],
//   C/D: col=lane&15, row=(lane>>4)*4+reg.
// bp layout per 16-bin chunk (32 K-cols): 2048B = [64 lanes x 16B re][64 x 16B im]
// global_load_lds: per-lane GLOBAL gather ok; LDS side wave-uniform base,
// lane l lands at base + l*16 (guide m97/m104/m108).

namespace {
constexpr int kSR    = 22050;
constexpr int kHop   = 512;
constexpr int kBins  = 168;
constexpr int kT     = 689;
constexpr int kB     = 4;
constexpr int kS     = 352768;
constexpr float kKScale    = 4096.0f;
constexpr float kKScaleInv = 1.0f / 4096.0f;
constexpr int kG16 = 11;              // 16-bin groups (g10 = bins 160..167)
constexpr int kAcc = kB * kT * kBins * 2;   // unpadded split-K accumulator
// path B layout
constexpr int kTPadB   = 768;
constexpr int kBinPadB = 176;
constexpr int kAccB    = kB * kTPadB * kBinPadB * 2;
}

typedef _Float16 half8 __attribute__((ext_vector_type(8)));
typedef _Float16 half2v __attribute__((ext_vector_type(2)));
typedef float floatx4 __attribute__((ext_vector_type(4)));

struct Jobs {          // path B job table
  int k0[48];
  int lo[48];
  int hi[48];
  int n;
};

struct JobsC {         // path A tables
  int lo16[kG16];      // support start col per 16-bin group (256-aligned)
  int cb16[kG16];      // chunk-prefix per group (bp indexing)
  int mlo[3];          // macro-group (64-bin) support start col
  int sm[24];          // per slice: macro id
  int slo[24];         // per slice: chunk range [slo,shi) rel. to mlo (even)
  int shi[24];
  int ns;
  int totch;
};

__device__ inline void atomAddF(float* p, float v) {
  __hip_atomic_fetch_add(p, v, __ATOMIC_RELAXED, __HIP_MEMORY_SCOPE_AGENT);
}

typedef __attribute__((address_space(3))) unsigned int lds_uint;
typedef __attribute__((address_space(1))) const unsigned int glb_uint;
__device__ __forceinline__ void dma16(const void* g, void* l) {
  __builtin_amdgcn_global_load_lds((glb_uint*)g, (lds_uint*)l, 16, 0, 0);
}

// ---- fused prep: [0,nbx) audio | [nbx,nbx+nbp) bpack | rest zero acc ----
__global__ __launch_bounds__(256) void prep_fused(
    const float* __restrict__ x, const float* __restrict__ kr,
    const float* __restrict__ ki, _Float16* __restrict__ xp,
    _Float16* __restrict__ bp, float* __restrict__ accb,
    const int pad, const int xps, const int nmax,
    const int nbx, const int nbp, const JobsC jt) {
  int bid = blockIdx.x;
  const int tid = threadIdx.x;

  if (bid < nbx) {
    // --- padded f16 audio: 8 elements/thread, one 16B store ---
    const int octx = xps >> 3;
    const int gid = bid * 256 + tid;
    if (gid >= kB * octx) return;
    const int b = gid / octx;
    const int i = (gid - b * octx) * 8;
    const float* xb = x + (size_t)b * kS - pad;
    half8 h;
    #pragma unroll
    for (int j = 0; j < 8; ++j) {
      const int e = i + j;
      h[j] = (e >= pad && e < pad + kS) ? (_Float16)xb[e] : (_Float16)0.f;
    }
    *(half8*)&xp[(size_t)b * xps + i] = h;
    return;
  }
  bid -= nbx;

  if (bid < nbp) {
    // --- B-fragment pack: 64 threads -> one 16-bin chunk (re+im) ---
    const int chunkid = bid * 4 + (tid >> 6);
    const int lane = tid & 63;
    if (chunkid >= jt.totch) return;
    int g = 0;
    #pragma unroll
    for (int j = 1; j < kG16; ++j)
      if (chunkid >= jt.cb16[j]) g = j;
    const int c = chunkid - jt.cb16[g];
    const int mm = lane & 15;
    const int q  = lane >> 4;
    const int bin  = g * 16 + mm;
    const int col0 = jt.lo16[g] + c * 32 + q * 8;
    const bool binok = (bin < kBins);
    const float* rowr = kr + (size_t)bin * nmax;
    const float* rowi = ki + (size_t)bin * nmax;
    half8 hre, him;
    #pragma unroll
    for (int j = 0; j < 8; ++j) {
      const int col = col0 + j;
      const bool ok = binok && (col < nmax);
      hre[j] = ok ? (_Float16)(rowr[col] * kKScale) : (_Float16)0.f;
      him[j] = ok ? (_Float16)(rowi[col] * kKScale) : (_Float16)0.f;
    }
    _Float16* dst = bp + (size_t)chunkid * 1024 + lane * 8;
    *(half8*)dst = hre;
    *(half8*)(dst + 512) = him;
    return;
  }
  bid -= nbp;

  // --- zero split-K accumulator ---
  const int idx = (bid * 256 + tid) * 4;
  if (idx < kAcc)
    *(floatx4*)&accb[idx] = (floatx4){0.f, 0.f, 0.f, 0.f};
}

// ---- path A main: async-DMA double-buffered MFMA, 32-frame WGs ----
// LDS per buffer (halfs): A regions [cc(2)][tl(2)] x 512 at 0..2047;
//                         B regions [wave(4)][cc(2)][re/im] x 512 at 2048..10239.
__global__ __launch_bounds__(256) void cqt_mfma9(
    const _Float16* __restrict__ bp, const _Float16* __restrict__ xp,
    float* __restrict__ accb, const int xps, const JobsC jt) {
  __shared__ _Float16 lds[2][10240];   // 2 x 20 KB

  const int sx = blockIdx.y;
  const int fb = blockIdx.x >> 2;      // 0..21 (32 frames each)
  const int b  = blockIdx.x & 3;
  const int tid  = threadIdx.x;
  const int wave = tid >> 6;
  const int lane = tid & 63;
  const int mm = lane & 15;
  const int q  = lane >> 4;
  const int mac = jt.sm[sx];
  const int g16 = mac * 4 + wave;
  const bool gvalid = (g16 < kG16);
  const int mlo = jt.mlo[mac];
  const int gs = gvalid ? ((jt.lo16[g16] - mlo) >> 5) : 0x7fffffff;
  const int slo = jt.slo[sx];
  const int shi = jt.shi[sx];
  const int fbase = fb * 32;

  // A-DMA source geometry: wave w stages region idx=w (cc=w>>1, tl=w&1)
  const _Float16* xb = xp + (size_t)b * xps;
  int aoff;
  {
    const int tl = wave & 1;
    int row = fbase + tl * 16 + mm;
    if (row > kT - 1) row = kT - 1;
    aoff = row * kHop + q * 8 + ((wave >> 1) * 32);
  }
  const _Float16* bgrp =
      gvalid ? (bp + (size_t)(jt.cb16[g16] - gs) * 1024 + lane * 8) : bp;

  floatx4 accr[2], acci[2];
  #pragma unroll
  for (int tl = 0; tl < 2; ++tl) {
    accr[tl] = (floatx4){0.f, 0.f, 0.f, 0.f};
    acci[tl] = (floatx4){0.f, 0.f, 0.f, 0.f};
  }

  auto stageDMA = [&](int c, int buf) {
    _Float16* L = lds[buf];
    // A: 1 inst per wave; lane l lands at base + l*16 (HW rule)
    dma16(xb + mlo + c * 32 + aoff, L + wave * 512);
    // B: my group's 2 chunks x re/im
    if (gvalid && c >= gs) {
      const _Float16* bs = bgrp + (size_t)c * 1024;
      #pragma unroll
      for (int cc = 0; cc < 2; ++cc)
        #pragma unroll
        for (int ri = 0; ri < 2; ++ri)
          dma16(bs + cc * 1024 + ri * 512,
                L + 2048 + (wave * 4 + cc * 2 + ri) * 512);
    }
  };

  auto compute = [&](int c, int buf) {
    if (!gvalid || c < gs) return;
    const _Float16* L = lds[buf];
    #pragma unroll
    for (int cc = 0; cc < 2; ++cc) {
      const half8 Bre = *(const half8*)(L + 2048 + (wave * 4 + cc * 2) * 512 + lane * 8);
      const half8 Bim = *(const half8*)(L + 2048 + (wave * 4 + cc * 2 + 1) * 512 + lane * 8);
      #pragma unroll
      for (int tl = 0; tl < 2; ++tl) {
        const half8 A = *(const half8*)(L + (cc * 2 + tl) * 512 + lane * 8);
        accr[tl] = __builtin_amdgcn_mfma_f32_16x16x32_f16(A, Bre, accr[tl], 0, 0, 0);
        acci[tl] = __builtin_amdgcn_mfma_f32_16x16x32_f16(A, Bim, acci[tl], 0, 0, 0);
      }
    }
  };

  // 2-barrier double-buffered pipeline (m97 structure, verified R9/R12)
  stageDMA(slo, 0);
  int buf = 0;
  #pragma unroll 1
  for (int c = slo; c < shi; c += 2) {
    __syncthreads();                       // drains this stage's DMA (vmcnt)
    if (c + 2 < shi) stageDMA(c + 2, buf ^ 1);
    compute(c, buf);
    buf ^= 1;
  }

  // epilogue: un-scale + guarded split-K atomic combine (fire-and-forget)
  const int bin = g16 * 16 + mm;
  if (bin < kBins) {
    #pragma unroll
    for (int tl = 0; tl < 2; ++tl) {
      const int tb = fbase + tl * 16 + q * 4;
      #pragma unroll
      for (int r = 0; r < 4; ++r) {
        const int t = tb + r;
        if (t < kT) {
          const size_t o = (((size_t)b * kT + t) * kBins + bin) * 2;
          atomAddF(&accb[o],     accr[tl][r] * kKScaleInv);
          atomAddF(&accb[o + 1], acci[tl][r] * kKScaleInv);
        }
      }
    }
  }
}

// ---- final: magnitude, 4 outputs/thread (path A tight layout) ----
__global__ __launch_bounds__(256) void cqt_mag4(
    const float* __restrict__ accb, float* __restrict__ out) {
  const int gid = (blockIdx.x * 256 + threadIdx.x) * 4;
  if (gid >= kB * kT * kBins) return;
  const floatx4 v0 = *(const floatx4*)&accb[gid * 2];
  const floatx4 v1 = *(const floatx4*)&accb[gid * 2 + 4];
  floatx4 o;
  o[0] = sqrtf(v0[0] * v0[0] + v0[1] * v0[1]);
  o[1] = sqrtf(v0[2] * v0[2] + v0[3] * v0[3]);
  o[2] = sqrtf(v1[0] * v1[0] + v1[1] * v1[1]);
  o[3] = sqrtf(v1[2] * v1[2] + v1[3] * v1[3]);
  *(floatx4*)&out[gid] = o;
}

// ---- final: magnitude (layout-parametric, path B) ----
__global__ __launch_bounds__(256) void cqt_mag_final(
    const float* __restrict__ accb, float* __restrict__ out,
    const int tp, const int kp) {
  int gid = blockIdx.x * 256 + threadIdx.x;
  if (gid >= kB * kT * kBins) return;
  const int k = gid % kBins;
  const int r = gid / kBins;
  const int t = r % kT;
  const int b = r / kT;
  const float2 v = ((const float2*)accb)[((size_t)b * tp + t) * kp + k];
  out[gid] = sqrtf(v.x * v.x + v.y * v.y);
}

// ================= path B: round-3 LDS-staging MFMA (verified) =============
__global__ __launch_bounds__(256) void prep_x_kernel(
    const float* __restrict__ x, _Float16* __restrict__ xp,
    const int pad, const int xps) {
  const int halfx = xps >> 1;
  int gid = blockIdx.x * 256 + threadIdx.x;
  if (gid >= kB * halfx) return;
  const int b = gid / halfx;
  const int i = (gid - b * halfx) * 2;
  float v0 = 0.f, v1 = 0.f;
  if (i     >= pad && i     < pad + kS) v0 = x[(size_t)b * kS + (i - pad)];
  if (i + 1 >= pad && i + 1 < pad + kS) v1 = x[(size_t)b * kS + (i + 1 - pad)];
  half2v h; h.x = (_Float16)v0; h.y = (_Float16)v1;
  *(half2v*)&xp[(size_t)b * xps + i] = h;
}

__global__ __launch_bounds__(256) void cqt_mfma_kernel(
    const float* __restrict__ kr, const float* __restrict__ ki,
    const _Float16* __restrict__ xp, float* __restrict__ accb,
    const int nmax, const int xps, const Jobs jt) {
  __shared__ _Float16 Bs[2][16][264];
  const int jb = blockIdx.x;
  const int k0   = jt.k0[jb];
  const int n_lo = jt.lo[jb];
  const int n_hi = jt.hi[jb];
  const int b  = blockIdx.z;
  const int fb = blockIdx.y;
  const int tid  = threadIdx.x;
  const int lane = tid & 63;
  const int wave = tid >> 6;
  const int m = lane & 15;
  const int q = lane >> 4;
  const int sbin = tid >> 4;
  const int scol = tid & 15;
  const int gbin = k0 + sbin;
  const bool binok = (gbin < kBins);
  const float* rowr = kr + (size_t)gbin * nmax;
  const float* rowi = ki + (size_t)gbin * nmax;
  const int fbase = fb * 256 + wave * 64;
  const _Float16* ax =
      xp + (size_t)b * xps + (size_t)(fbase + m) * kHop + q * 8;
  floatx4 accr[4], acci[4];
  #pragma unroll
  for (int tl = 0; tl < 4; ++tl) {
    accr[tl] = (floatx4){0.f, 0.f, 0.f, 0.f};
    acci[tl] = (floatx4){0.f, 0.f, 0.f, 0.f};
  }
  for (int n0r = n_lo; n0r < n_hi; n0r += 256) {
    __syncthreads();
    #pragma unroll
    for (int c = 0; c < 16; ++c) {
      const int col = n0r + scol + c * 16;
      const bool ok = binok && (col < nmax);
      const float vr = ok ? rowr[col] : 0.f;
      const float vi = ok ? rowi[col] : 0.f;
      Bs[0][sbin][scol + c * 16] = (_Float16)(vr * kKScale);
      Bs[1][sbin][scol + c * 16] = (_Float16)(vi * kKScale);
    }
    __syncthreads();
    const _Float16* axr = ax + n0r;
    #pragma unroll
    for (int c = 0; c < 8; ++c) {
      const int ko = c * 32 + q * 8;
      const half8 br = *(const half8*)&Bs[0][m][ko];
      const half8 bi = *(const half8*)&Bs[1][m][ko];
      #pragma unroll
      for (int tl = 0; tl < 4; ++tl) {
        const half8 a = *(const half8*)(axr + tl * 16 * kHop + c * 32);
        accr[tl] = __builtin_amdgcn_mfma_f32_16x16x32_f16(a, br, accr[tl], 0, 0, 0);
        acci[tl] = __builtin_amdgcn_mfma_f32_16x16x32_f16(a, bi, acci[tl], 0, 0, 0);
      }
    }
  }
  #pragma unroll
  for (int tl = 0; tl < 4; ++tl) {
    #pragma unroll
    for (int rr = 0; rr < 4; ++rr) {
      const int t = fbase + tl * 16 + q * 4 + rr;
      const size_t o = (((size_t)b * kTPadB + t) * kBinPadB + (k0 + m)) * 2;
      atomAddF(&accb[o],     accr[tl][rr] * kKScaleInv);
      atomAddF(&accb[o + 1], acci[tl][rr] * kKScaleInv);
    }
  }
}

// ================= path C: verified fp32 kernel (round 2) ==================
namespace fb32 {
constexpr int TT = 8;
constexpr int KG = 4;
constexpr int kTTiles  = (kT + TT - 1) / TT;
constexpr int kKGroups = kBins / KG;
constexpr int kWaves   = kB * kTTiles * kKGroups;
}

__global__ __launch_bounds__(256) void cqt_mag_kernel(
    const float* __restrict__ x,
    const float* __restrict__ kr,
    const float* __restrict__ ki,
    float* __restrict__ out,
    const int nmax, const int pad) {
  using namespace fb32;
  const int wave = (blockIdx.x << 2) + (threadIdx.x >> 6);
  const int lane = threadIdx.x & 63;
  if (wave >= kWaves) return;
  const int kg    = wave / (kB * kTTiles);
  const int rem   = wave - kg * (kB * kTTiles);
  const int b     = rem / kTTiles;
  const int ttile = rem - b * kTTiles;
  const int k0 = kg * KG;
  const int t0 = ttile * TT;
  const double Q  = 1.0 / (exp2(1.0 / 24.0) - 1.0);
  const double f0 = 32.7 * exp2((double)k0 / 24.0);
  int N = (int)ceil(Q * (double)kSR / f0) + 8;
  int full_start = nmax - N;
  if (full_start < 0) full_start = 0;
  int tbase[TT], lo[TT], t_last;
  { int t = t0 + TT - 1; if (t > kT - 1) t = kT - 1; t_last = t; }
  #pragma unroll
  for (int tt = 0; tt < TT; ++tt) {
    int t = t0 + tt; if (t > kT - 1) t = kT - 1;
    tbase[tt] = b * kS + t * kHop - pad;
    lo[tt]    = pad - t * kHop;
  }
  int head_start = pad - t_last * kHop;
  if (head_start < full_start) head_start = full_start;
  int safe = pad - t0 * kHop;
  if (safe < head_start) safe = head_start;
  int body_start = nmax - ((nmax - safe) & ~63);
  float accr[TT][KG], acci[TT][KG];
  #pragma unroll
  for (int tt = 0; tt < TT; ++tt)
    #pragma unroll
    for (int kk = 0; kk < KG; ++kk) { accr[tt][kk] = 0.f; acci[tt][kk] = 0.f; }
  for (int n = body_start - 64; n > head_start - 64; n -= 64) {
    const int nn = n + lane;
    const bool kok = (nn >= 0);
    float krv[KG], kiv[KG];
    #pragma unroll
    for (int kk = 0; kk < KG; ++kk) {
      krv[kk] = kok ? kr[(k0 + kk) * nmax + nn] : 0.f;
      kiv[kk] = kok ? ki[(k0 + kk) * nmax + nn] : 0.f;
    }
    float a[TT];
    #pragma unroll
    for (int tt = 0; tt < TT; ++tt)
      a[tt] = (nn >= lo[tt]) ? x[tbase[tt] + nn] : 0.f;
    #pragma unroll
    for (int tt = 0; tt < TT; ++tt)
      #pragma unroll
      for (int kk = 0; kk < KG; ++kk) {
        accr[tt][kk] = fmaf(a[tt], krv[kk], accr[tt][kk]);
        acci[tt][kk] = fmaf(a[tt], kiv[kk], acci[tt][kk]);
      }
  }
  for (int n = body_start; n < nmax; n += 64) {
    const int nn = n + lane;
    float krv[KG], kiv[KG];
    #pragma unroll
    for (int kk = 0; kk < KG; ++kk) {
      krv[kk] = kr[(k0 + kk) * nmax + nn];
      kiv[kk] = ki[(k0 + kk) * nmax + nn];
    }
    float a[TT];
    #pragma unroll
    for (int tt = 0; tt < TT; ++tt)
      a[tt] = x[tbase[tt] + nn];
    #pragma unroll
    for (int tt = 0; tt < TT; ++tt)
      #pragma unroll
      for (int kk = 0; kk < KG; ++kk) {
        accr[tt][kk] = fmaf(a[tt], krv[kk], accr[tt][kk]);
        acci[tt][kk] = fmaf(a[tt], kiv[kk], acci[tt][kk]);
      }
  }
  #pragma unroll
  for (int tt = 0; tt < TT; ++tt) {
    #pragma unroll
    for (int kk = 0; kk < KG; ++kk) {
      float r = accr[tt][kk];
      float i = acci[tt][kk];
      #pragma unroll
      for (int s = 32; s > 0; s >>= 1) {
        r += __shfl_xor(r, s, 64);
        i += __shfl_xor(i, s, 64);
      }
      if (lane == 0) {
        const int t = t0 + tt;
        if (t < kT)
          out[(b * kT + t) * kBins + (k0 + kk)] = sqrtf(r * r + i * i);
      }
    }
  }
}
// ============================================================================

extern "C" void kernel_launch(void* const* d_in, const int* in_sizes, int n_in,
                              void* d_out, int out_size, void* d_ws, size_t ws_size,
                              hipStream_t stream) {
  const float* x  = (const float*)d_in[0];   // [4, 1, 352768]
  const float* kr = (const float*)d_in[1];   // [168, nmax]
  const float* ki = (const float*)d_in[2];   // [168, nmax]
  float* out = (float*)d_out;                // [4, 1, 689, 168]

  const int nmax = in_sizes[1] / kBins;      // 23013 (runtime truth)
  const int pad  = nmax - kHop;

  const int kcap = ((nmax + 255) / 256) * 256;   // 23040
  const double Q = 1.0 / (exp2(1.0 / 24.0) - 1.0);

  // ---- path A tables ----
  JobsC jc;
  int tot = 0;
  for (int g = 0; g < kG16; ++g) {
    const double f0 = 32.7 * exp2((double)(16 * g) / 24.0);
    const int N = (int)ceil(Q * (double)kSR / f0) + 8;
    int lo = nmax - N;
    if (lo < 0) lo = 0;
    lo &= ~255;
    jc.lo16[g] = lo;
    jc.cb16[g] = tot;
    tot += (kcap - lo) / 32;
  }
  jc.totch = tot;                        // ~1980 chunks
  // ns=11 slice table (R9/R12-verified optimum: 8/2/1 slices, <=96 chunks)
  int ns = 0;
  for (int m = 0; m < 3; ++m) {
    jc.mlo[m] = jc.lo16[4 * m];
    const int C = (kcap - jc.mlo[m]) / 32;       // 720 / 120 / 24
    const int nsl = (C + 95) / 96;               // 8 / 2 / 1
    const int len = ((C + nsl - 1) / nsl + 1) & ~1;
    for (int s = 0; s < nsl && ns < 24; ++s) {
      const int lo = s * len;
      if (lo >= C) break;
      int hi = lo + len;
      if (hi > C) hi = C;
      jc.sm[ns] = m; jc.slo[ns] = lo; jc.shi[ns] = hi;
      ++ns;
    }
  }
  jc.ns = ns;                            // 11 expected

  // ---- path A ws layout ----
  const int xpsA = (kT - 1) * kHop + kcap + 256;           // 375,552 (%8==0)
  const size_t xpA_bytes = (size_t)kB * xpsA * sizeof(_Float16);
  const size_t accA_off  = (xpA_bytes + 511) & ~(size_t)511;
  const size_t accA_bytes = (size_t)kAcc * sizeof(float);
  const size_t bpA_off   = (accA_off + accA_bytes + 511) & ~(size_t)511;
  const size_t bpA_bytes = (size_t)tot * 2048;
  const size_t ws_A = bpA_off + bpA_bytes;                 // ~10.8 MB

  // ---- path B layout ----
  const int xpsB = (kTPadB - 1) * kHop + kcap + 256;
  const size_t xpB_bytes = (size_t)kB * xpsB * sizeof(_Float16);
  const size_t accB_off  = (xpB_bytes + 511) & ~(size_t)511;
  const size_t accB_bytes = (size_t)kAccB * sizeof(float);
  const size_t ws_B = accB_off + accB_bytes;

  if (ws_size >= ws_A) {
    // ---- path A: 3 dispatches ----
    _Float16* xp = (_Float16*)d_ws;
    float* accb  = (float*)((char*)d_ws + accA_off);
    _Float16* bp = (_Float16*)((char*)d_ws + bpA_off);

    const int nbx = (kB * (xpsA / 8) + 255) / 256;   // audio blocks (8 el/thr)
    const int nbp = (tot + 3) / 4;                   // bpack blocks (4 chunks ea)
    const int nba = (kAcc / 4 + 255) / 256;          // acc-zero blocks
    prep_fused<<<nbx + nbp + nba, 256, 0, stream>>>(
        x, kr, ki, xp, bp, accb, pad, xpsA, nmax, nbx, nbp, jc);

    {
      dim3 grid(88, ns);   // x = fb(22) * b(4); y = balanced K-slices (ns=11)
      cqt_mfma9<<<grid, 256, 0, stream>>>(bp, xp, accb, xpsA, jc);
    }
    {
      const int total = kB * kT * kBins;       // 463,008 (% 4 == 0)
      cqt_mag4<<<(total / 4 + 255) / 256, 256, 0, stream>>>(accb, out);
    }
    return;
  }

  if (ws_size >= ws_B) {
    // ---- path B (round-3, verified ~224us) ----
    _Float16* xp = (_Float16*)d_ws;
    float* accb  = (float*)((char*)d_ws + accB_off);
    Jobs jt;
    int nj = 0;
    for (int g = 0; g < 11; ++g) {
      const int gk0 = 16 * g;
      const double f0 = 32.7 * exp2((double)gk0 / 24.0);
      const int N = (int)ceil(Q * (double)kSR / f0) + 8;
      int lo = nmax - N;
      if (lo < 0) lo = 0;
      lo = (lo / 2048) * 2048;
      for (int s = lo; s < kcap && nj < 48; s += 2048) {
        jt.k0[nj] = gk0;
        jt.lo[nj] = s;
        jt.hi[nj] = (s + 2048 < kcap) ? s + 2048 : kcap;
        ++nj;
      }
    }
    jt.n = nj;
    hipMemsetAsync(accb, 0, accB_bytes, stream);
    {
      const int total = kB * (xpsB / 2);
      prep_x_kernel<<<(total + 255) / 256, 256, 0, stream>>>(x, xp, pad, xpsB);
    }
    {
      dim3 grid(nj, kTPadB / 256, kB);
      cqt_mfma_kernel<<<grid, 256, 0, stream>>>(kr, ki, xp, accb, nmax, xpsB, jt);
    }
    {
      const int total = kB * kT * kBins;
      cqt_mag_final<<<(total + 255) / 256, 256, 0, stream>>>(
          accb, out, kTPadB, kBinPadB);
    }
    return;
  }

  // ---- path C: fp32 fallback ----
  {
    const int blocks = fb32::kWaves / 4;
    cqt_mag_kernel<<<blocks, 256, 0, stream>>>(x, kr, ki, out, nmax, pad);
  }
}

// Round 14
// 121.728 us; speedup vs baseline: 1.7502x; 1.0551x over previous
//
#include <hip/hip_runtime.h>
#include <math.h>

// HarmonicCQT via f16 MFMA: out[b,t,k] = |sum_n xpad[t*512+n] * (kr[k,n]+i*ki[k,n])|
//
// Path P (ws >= ~14.95MB), 3 dispatches, NO atomics:
//   1. prep_fused   : audio->f16 xp + B-fragment pack (no acc-zero needed)
//   2. cqt_mfma_t<true> : R13's verified async-DMA double-buffered K-loop;
//        epilogue = 2x16B f16 partial stores to an exclusive per-(slice,fb,b,
//        wave) region (replaces the ~38us agent-atomic drain: measured cost
//        model t = 0.22us/iter + 9.7us/M-atomic from R11/R12/R13).
//   3. cqt_mag_part : sum 8/2/1 slice partials (coalesced) -> magnitude -> out
// Path A (ws >= ~10.8MB): exact R13 atomic path (main 47us, total ~128us).
// Path B (ws >= ~7.7MB): round-3 LDS-staging MFMA kernel (verified, ~224us).
// Path C: verified fp32 kernel (~370us).
//
// MFMA 16x16x32 layouts (verified rounds 3-13, absmax 4.9e-4):
//   A[m=lane&15][k=(lane>>4)*8+j], B[k=(lane>>4)*8+j][n=lane&15],
//   C/D: col=lane&15, row=(lane>>4)*4+reg.
// bp layout per 16-bin chunk (32 K-cols): 2048B = [64 lanes x 16B re][64 x 16B im]
// Partial layout: slot = ((sx*88 + fb*4+b)*4 + wave); 1024 halfs per slot,
// lane l at slot*1024 + l*16, within-lane order [tl][r][re/im].

namespace {
constexpr int kSR    = 22050;
constexpr int kHop   = 512;
constexpr int kBins  = 168;
constexpr int kT     = 689;
constexpr int kB     = 4;
constexpr int kS     = 352768;
constexpr float kKScale    = 4096.0f;
constexpr float kKScaleInv = 1.0f / 4096.0f;
constexpr int kG16 = 11;              // 16-bin groups (g10 = bins 160..167)
constexpr int kFBB = 88;              // fb(22) * b(4)
constexpr int kAcc = kB * kT * kBins * 2;   // path-A split-K accumulator
// path B layout
constexpr int kTPadB   = 768;
constexpr int kBinPadB = 176;
constexpr int kAccB    = kB * kTPadB * kBinPadB * 2;
}

typedef _Float16 half8 __attribute__((ext_vector_type(8)));
typedef _Float16 half2v __attribute__((ext_vector_type(2)));
typedef float floatx4 __attribute__((ext_vector_type(4)));

struct Jobs {          // path B job table
  int k0[48];
  int lo[48];
  int hi[48];
  int n;
};

struct JobsC {         // path P/A tables
  int lo16[kG16];      // support start col per 16-bin group (256-aligned)
  int cb16[kG16];      // chunk-prefix per group (bp indexing)
  int mlo[3];          // macro-group (64-bin) support start col
  int sm[24];          // per slice: macro id
  int slo[24];         // per slice: chunk range [slo,shi) rel. to mlo (even)
  int shi[24];
  int sbeg[3];         // first slice index of macro
  int scnt[3];         // slice count of macro
  int ns;
  int totch;
};

__device__ inline void atomAddF(float* p, float v) {
  __hip_atomic_fetch_add(p, v, __ATOMIC_RELAXED, __HIP_MEMORY_SCOPE_AGENT);
}

typedef __attribute__((address_space(3))) unsigned int lds_uint;
typedef __attribute__((address_space(1))) const unsigned int glb_uint;
__device__ __forceinline__ void dma16(const void* g, void* l) {
  __builtin_amdgcn_global_load_lds((glb_uint*)g, (lds_uint*)l, 16, 0, 0);
}

// ---- fused prep: [0,nbx) audio | [nbx,nbx+nbp) bpack | [.., +nba) zero acc ----
__global__ __launch_bounds__(256) void prep_fused(
    const float* __restrict__ x, const float* __restrict__ kr,
    const float* __restrict__ ki, _Float16* __restrict__ xp,
    _Float16* __restrict__ bp, float* __restrict__ accb,
    const int pad, const int xps, const int nmax,
    const int nbx, const int nbp, const JobsC jt) {
  int bid = blockIdx.x;
  const int tid = threadIdx.x;

  if (bid < nbx) {
    // --- padded f16 audio: 8 elements/thread, one 16B store ---
    const int octx = xps >> 3;
    const int gid = bid * 256 + tid;
    if (gid >= kB * octx) return;
    const int b = gid / octx;
    const int i = (gid - b * octx) * 8;
    const float* xb = x + (size_t)b * kS - pad;
    half8 h;
    #pragma unroll
    for (int j = 0; j < 8; ++j) {
      const int e = i + j;
      h[j] = (e >= pad && e < pad + kS) ? (_Float16)xb[e] : (_Float16)0.f;
    }
    *(half8*)&xp[(size_t)b * xps + i] = h;
    return;
  }
  bid -= nbx;

  if (bid < nbp) {
    // --- B-fragment pack: 64 threads -> one 16-bin chunk (re+im) ---
    const int chunkid = bid * 4 + (tid >> 6);
    const int lane = tid & 63;
    if (chunkid >= jt.totch) return;
    int g = 0;
    #pragma unroll
    for (int j = 1; j < kG16; ++j)
      if (chunkid >= jt.cb16[j]) g = j;
    const int c = chunkid - jt.cb16[g];
    const int mm = lane & 15;
    const int q  = lane >> 4;
    const int bin  = g * 16 + mm;
    const int col0 = jt.lo16[g] + c * 32 + q * 8;
    const bool binok = (bin < kBins);
    const float* rowr = kr + (size_t)bin * nmax;
    const float* rowi = ki + (size_t)bin * nmax;
    half8 hre, him;
    #pragma unroll
    for (int j = 0; j < 8; ++j) {
      const int col = col0 + j;
      const bool ok = binok && (col < nmax);
      hre[j] = ok ? (_Float16)(rowr[col] * kKScale) : (_Float16)0.f;
      him[j] = ok ? (_Float16)(rowi[col] * kKScale) : (_Float16)0.f;
    }
    _Float16* dst = bp + (size_t)chunkid * 1024 + lane * 8;
    *(half8*)dst = hre;
    *(half8*)(dst + 512) = him;
    return;
  }
  bid -= nbp;

  // --- zero split-K accumulator (path A only; nba=0 in path P) ---
  const int idx = (bid * 256 + tid) * 4;
  if (idx < kAcc)
    *(floatx4*)&accb[idx] = (floatx4){0.f, 0.f, 0.f, 0.f};
}

// ---- main: async-DMA double-buffered MFMA, 32-frame WGs (R13-verified) ----
// PARTIAL=true : epilogue = exclusive f16 partial stores (no atomics)
// PARTIAL=false: epilogue = guarded agent-atomic split-K (R13 behavior)
// LDS per buffer (halfs): A [cc(2)][tl(2)] x 512 at 0..2047;
//                         B [wave(4)][cc(2)][re/im] x 512 at 2048..10239.
template <bool PARTIAL>
__global__ __launch_bounds__(256) void cqt_mfma_t(
    const _Float16* __restrict__ bp, const _Float16* __restrict__ xp,
    float* __restrict__ accb, _Float16* __restrict__ part,
    const int xps, const JobsC jt) {
  __shared__ _Float16 lds[2][10240];   // 2 x 20 KB

  const int sx = blockIdx.y;
  const int fb = blockIdx.x >> 2;      // 0..21 (32 frames each)
  const int b  = blockIdx.x & 3;
  const int tid  = threadIdx.x;
  const int wave = tid >> 6;
  const int lane = tid & 63;
  const int mm = lane & 15;
  const int q  = lane >> 4;
  const int mac = jt.sm[sx];
  const int g16 = mac * 4 + wave;
  const bool gvalid = (g16 < kG16);
  const int mlo = jt.mlo[mac];
  const int gs = gvalid ? ((jt.lo16[g16] - mlo) >> 5) : 0x7fffffff;
  const int slo = jt.slo[sx];
  const int shi = jt.shi[sx];
  const int fbase = fb * 32;

  // A-DMA source geometry: wave w stages region idx=w (cc=w>>1, tl=w&1)
  const _Float16* xb = xp + (size_t)b * xps;
  int aoff;
  {
    const int tl = wave & 1;
    int row = fbase + tl * 16 + mm;
    if (row > kT - 1) row = kT - 1;
    aoff = row * kHop + q * 8 + ((wave >> 1) * 32);
  }
  const _Float16* bgrp =
      gvalid ? (bp + (size_t)(jt.cb16[g16] - gs) * 1024 + lane * 8) : bp;

  floatx4 accr[2], acci[2];
  #pragma unroll
  for (int tl = 0; tl < 2; ++tl) {
    accr[tl] = (floatx4){0.f, 0.f, 0.f, 0.f};
    acci[tl] = (floatx4){0.f, 0.f, 0.f, 0.f};
  }

  auto stageDMA = [&](int c, int buf) {
    _Float16* L = lds[buf];
    dma16(xb + mlo + c * 32 + aoff, L + wave * 512);
    if (gvalid && c >= gs) {
      const _Float16* bs = bgrp + (size_t)c * 1024;
      #pragma unroll
      for (int cc = 0; cc < 2; ++cc)
        #pragma unroll
        for (int ri = 0; ri < 2; ++ri)
          dma16(bs + cc * 1024 + ri * 512,
                L + 2048 + (wave * 4 + cc * 2 + ri) * 512);
    }
  };

  auto compute = [&](int c, int buf) {
    if (!gvalid || c < gs) return;
    const _Float16* L = lds[buf];
    #pragma unroll
    for (int cc = 0; cc < 2; ++cc) {
      const half8 Bre = *(const half8*)(L + 2048 + (wave * 4 + cc * 2) * 512 + lane * 8);
      const half8 Bim = *(const half8*)(L + 2048 + (wave * 4 + cc * 2 + 1) * 512 + lane * 8);
      #pragma unroll
      for (int tl = 0; tl < 2; ++tl) {
        const half8 A = *(const half8*)(L + (cc * 2 + tl) * 512 + lane * 8);
        accr[tl] = __builtin_amdgcn_mfma_f32_16x16x32_f16(A, Bre, accr[tl], 0, 0, 0);
        acci[tl] = __builtin_amdgcn_mfma_f32_16x16x32_f16(A, Bim, acci[tl], 0, 0, 0);
      }
    }
  };

  // 2-barrier double-buffered pipeline (m97 structure, verified R9/R12/R13)
  stageDMA(slo, 0);
  int buf = 0;
  #pragma unroll 1
  for (int c = slo; c < shi; c += 2) {
    __syncthreads();                       // drains this stage's DMA (vmcnt)
    if (c + 2 < shi) stageDMA(c + 2, buf ^ 1);
    compute(c, buf);
    buf ^= 1;
  }

  if (PARTIAL) {
    // exclusive-region f16 partial stores: 2 x 16B per lane, no RMW
    _Float16* pw = part +
        (((size_t)sx * kFBB + blockIdx.x) * 4 + wave) * 1024 + lane * 16;
    half8 p0, p1;
    #pragma unroll
    for (int r = 0; r < 4; ++r) {
      p0[r * 2]     = (_Float16)accr[0][r];
      p0[r * 2 + 1] = (_Float16)acci[0][r];
      p1[r * 2]     = (_Float16)accr[1][r];
      p1[r * 2 + 1] = (_Float16)acci[1][r];
    }
    *(half8*)pw = p0;
    *(half8*)(pw + 8) = p1;
  } else {
    // guarded agent-atomic split-K combine (R13 path)
    const int bin = g16 * 16 + mm;
    if (bin < kBins) {
      #pragma unroll
      for (int tl = 0; tl < 2; ++tl) {
        const int tb = fbase + tl * 16 + q * 4;
        #pragma unroll
        for (int r = 0; r < 4; ++r) {
          const int t = tb + r;
          if (t < kT) {
            const size_t o = (((size_t)b * kT + t) * kBins + bin) * 2;
            atomAddF(&accb[o],     accr[tl][r] * kKScaleInv);
            atomAddF(&accb[o + 1], acci[tl][r] * kKScaleInv);
          }
        }
      }
    }
  }
}

// ---- path P final: sum slice partials -> magnitude -> out ----
__global__ __launch_bounds__(256) void cqt_mag_part(
    const _Float16* __restrict__ part, float* __restrict__ out,
    const JobsC jt) {
  const int fbb = blockIdx.x;          // 0..87
  const int fb = fbb >> 2;
  const int b  = fbb & 3;
  const int wave = threadIdx.x >> 6;
  const int lane = threadIdx.x & 63;
  const int g16 = blockIdx.y * 4 + wave;
  if (g16 >= kG16) return;
  const int mac = g16 >> 2;
  const int w   = g16 & 3;
  const int mm = lane & 15;
  const int q  = lane >> 4;

  float a[16];
  #pragma unroll
  for (int i = 0; i < 16; ++i) a[i] = 0.f;
  const int s0 = jt.sbeg[mac];
  const int s1 = s0 + jt.scnt[mac];
  #pragma unroll 1
  for (int s = s0; s < s1; ++s) {
    const _Float16* p = part +
        (((size_t)s * kFBB + fbb) * 4 + w) * 1024 + lane * 16;
    const half8 v0 = *(const half8*)p;
    const half8 v1 = *(const half8*)(p + 8);
    #pragma unroll
    for (int j = 0; j < 8; ++j) {
      a[j]     += (float)v0[j];
      a[8 + j] += (float)v1[j];
    }
  }
  const int k = g16 * 16 + mm;
  if (k >= kBins) return;
  #pragma unroll
  for (int tl = 0; tl < 2; ++tl) {
    #pragma unroll
    for (int r = 0; r < 4; ++r) {
      const int t = fb * 32 + tl * 16 + q * 4 + r;
      if (t < kT) {
        const float re = a[tl * 8 + r * 2];
        const float im = a[tl * 8 + r * 2 + 1];
        out[((size_t)b * kT + t) * kBins + k] =
            sqrtf(re * re + im * im) * kKScaleInv;
      }
    }
  }
}

// ---- path A final: magnitude, 4 outputs/thread ----
__global__ __launch_bounds__(256) void cqt_mag4(
    const float* __restrict__ accb, float* __restrict__ out) {
  const int gid = (blockIdx.x * 256 + threadIdx.x) * 4;
  if (gid >= kB * kT * kBins) return;
  const floatx4 v0 = *(const floatx4*)&accb[gid * 2];
  const floatx4 v1 = *(const floatx4*)&accb[gid * 2 + 4];
  floatx4 o;
  o[0] = sqrtf(v0[0] * v0[0] + v0[1] * v0[1]);
  o[1] = sqrtf(v0[2] * v0[2] + v0[3] * v0[3]);
  o[2] = sqrtf(v1[0] * v1[0] + v1[1] * v1[1]);
  o[3] = sqrtf(v1[2] * v1[2] + v1[3] * v1[3]);
  *(floatx4*)&out[gid] = o;
}

// ---- path B final: magnitude (layout-parametric) ----
__global__ __launch_bounds__(256) void cqt_mag_final(
    const float* __restrict__ accb, float* __restrict__ out,
    const int tp, const int kp) {
  int gid = blockIdx.x * 256 + threadIdx.x;
  if (gid >= kB * kT * kBins) return;
  const int k = gid % kBins;
  const int r = gid / kBins;
  const int t = r % kT;
  const int b = r / kT;
  const float2 v = ((const float2*)accb)[((size_t)b * tp + t) * kp + k];
  out[gid] = sqrtf(v.x * v.x + v.y * v.y);
}

// ================= path B: round-3 LDS-staging MFMA (verified) =============
__global__ __launch_bounds__(256) void prep_x_kernel(
    const float* __restrict__ x, _Float16* __restrict__ xp,
    const int pad, const int xps) {
  const int halfx = xps >> 1;
  int gid = blockIdx.x * 256 + threadIdx.x;
  if (gid >= kB * halfx) return;
  const int b = gid / halfx;
  const int i = (gid - b * halfx) * 2;
  float v0 = 0.f, v1 = 0.f;
  if (i     >= pad && i     < pad + kS) v0 = x[(size_t)b * kS + (i - pad)];
  if (i + 1 >= pad && i + 1 < pad + kS) v1 = x[(size_t)b * kS + (i + 1 - pad)];
  half2v h; h.x = (_Float16)v0; h.y = (_Float16)v1;
  *(half2v*)&xp[(size_t)b * xps + i] = h;
}

__global__ __launch_bounds__(256) void cqt_mfma_kernel(
    const float* __restrict__ kr, const float* __restrict__ ki,
    const _Float16* __restrict__ xp, float* __restrict__ accb,
    const int nmax, const int xps, const Jobs jt) {
  __shared__ _Float16 Bs[2][16][264];
  const int jb = blockIdx.x;
  const int k0   = jt.k0[jb];
  const int n_lo = jt.lo[jb];
  const int n_hi = jt.hi[jb];
  const int b  = blockIdx.z;
  const int fb = blockIdx.y;
  const int tid  = threadIdx.x;
  const int lane = tid & 63;
  const int wave = tid >> 6;
  const int m = lane & 15;
  const int q = lane >> 4;
  const int sbin = tid >> 4;
  const int scol = tid & 15;
  const int gbin = k0 + sbin;
  const bool binok = (gbin < kBins);
  const float* rowr = kr + (size_t)gbin * nmax;
  const float* rowi = ki + (size_t)gbin * nmax;
  const int fbase = fb * 256 + wave * 64;
  const _Float16* ax =
      xp + (size_t)b * xps + (size_t)(fbase + m) * kHop + q * 8;
  floatx4 accr[4], acci[4];
  #pragma unroll
  for (int tl = 0; tl < 4; ++tl) {
    accr[tl] = (floatx4){0.f, 0.f, 0.f, 0.f};
    acci[tl] = (floatx4){0.f, 0.f, 0.f, 0.f};
  }
  for (int n0r = n_lo; n0r < n_hi; n0r += 256) {
    __syncthreads();
    #pragma unroll
    for (int c = 0; c < 16; ++c) {
      const int col = n0r + scol + c * 16;
      const bool ok = binok && (col < nmax);
      const float vr = ok ? rowr[col] : 0.f;
      const float vi = ok ? rowi[col] : 0.f;
      Bs[0][sbin][scol + c * 16] = (_Float16)(vr * kKScale);
      Bs[1][sbin][scol + c * 16] = (_Float16)(vi * kKScale);
    }
    __syncthreads();
    const _Float16* axr = ax + n0r;
    #pragma unroll
    for (int c = 0; c < 8; ++c) {
      const int ko = c * 32 + q * 8;
      const half8 br = *(const half8*)&Bs[0][m][ko];
      const half8 bi = *(const half8*)&Bs[1][m][ko];
      #pragma unroll
      for (int tl = 0; tl < 4; ++tl) {
        const half8 a = *(const half8*)(axr + tl * 16 * kHop + c * 32);
        accr[tl] = __builtin_amdgcn_mfma_f32_16x16x32_f16(a, br, accr[tl], 0, 0, 0);
        acci[tl] = __builtin_amdgcn_mfma_f32_16x16x32_f16(a, bi, acci[tl], 0, 0, 0);
      }
    }
  }
  #pragma unroll
  for (int tl = 0; tl < 4; ++tl) {
    #pragma unroll
    for (int rr = 0; rr < 4; ++rr) {
      const int t = fbase + tl * 16 + q * 4 + rr;
      const size_t o = (((size_t)b * kTPadB + t) * kBinPadB + (k0 + m)) * 2;
      atomAddF(&accb[o],     accr[tl][rr] * kKScaleInv);
      atomAddF(&accb[o + 1], acci[tl][rr] * kKScaleInv);
    }
  }
}

// ================= path C: verified fp32 kernel (round 2) ==================
namespace fb32 {
constexpr int TT = 8;
constexpr int KG = 4;
constexpr int kTTiles  = (kT + TT - 1) / TT;
constexpr int kKGroups = kBins / KG;
constexpr int kWaves   = kB * kTTiles * kKGroups;
}

__global__ __launch_bounds__(256) void cqt_mag_kernel(
    const float* __restrict__ x,
    const float* __restrict__ kr,
    const float* __restrict__ ki,
    float* __restrict__ out,
    const int nmax, const int pad) {
  using namespace fb32;
  const int wave = (blockIdx.x << 2) + (threadIdx.x >> 6);
  const int lane = threadIdx.x & 63;
  if (wave >= kWaves) return;
  const int kg    = wave / (kB * kTTiles);
  const int rem   = wave - kg * (kB * kTTiles);
  const int b     = rem / kTTiles;
  const int ttile = rem - b * kTTiles;
  const int k0 = kg * KG;
  const int t0 = ttile * TT;
  const double Q  = 1.0 / (exp2(1.0 / 24.0) - 1.0);
  const double f0 = 32.7 * exp2((double)k0 / 24.0);
  int N = (int)ceil(Q * (double)kSR / f0) + 8;
  int full_start = nmax - N;
  if (full_start < 0) full_start = 0;
  int tbase[TT], lo[TT], t_last;
  { int t = t0 + TT - 1; if (t > kT - 1) t = kT - 1; t_last = t; }
  #pragma unroll
  for (int tt = 0; tt < TT; ++tt) {
    int t = t0 + tt; if (t > kT - 1) t = kT - 1;
    tbase[tt] = b * kS + t * kHop - pad;
    lo[tt]    = pad - t * kHop;
  }
  int head_start = pad - t_last * kHop;
  if (head_start < full_start) head_start = full_start;
  int safe = pad - t0 * kHop;
  if (safe < head_start) safe = head_start;
  int body_start = nmax - ((nmax - safe) & ~63);
  float accr[TT][KG], acci[TT][KG];
  #pragma unroll
  for (int tt = 0; tt < TT; ++tt)
    #pragma unroll
    for (int kk = 0; kk < KG; ++kk) { accr[tt][kk] = 0.f; acci[tt][kk] = 0.f; }
  for (int n = body_start - 64; n > head_start - 64; n -= 64) {
    const int nn = n + lane;
    const bool kok = (nn >= 0);
    float krv[KG], kiv[KG];
    #pragma unroll
    for (int kk = 0; kk < KG; ++kk) {
      krv[kk] = kok ? kr[(k0 + kk) * nmax + nn] : 0.f;
      kiv[kk] = kok ? ki[(k0 + kk) * nmax + nn] : 0.f;
    }
    float a[TT];
    #pragma unroll
    for (int tt = 0; tt < TT; ++tt)
      a[tt] = (nn >= lo[tt]) ? x[tbase[tt] + nn] : 0.f;
    #pragma unroll
    for (int tt = 0; tt < TT; ++tt)
      #pragma unroll
      for (int kk = 0; kk < KG; ++kk) {
        accr[tt][kk] = fmaf(a[tt], krv[kk], accr[tt][kk]);
        acci[tt][kk] = fmaf(a[tt], kiv[kk], acci[tt][kk]);
      }
  }
  for (int n = body_start; n < nmax; n += 64) {
    const int nn = n + lane;
    float krv[KG], kiv[KG];
    #pragma unroll
    for (int kk = 0; kk < KG; ++kk) {
      krv[kk] = kr[(k0 + kk) * nmax + nn];
      kiv[kk] = ki[(k0 + kk) * nmax + nn];
    }
    float a[TT];
    #pragma unroll
    for (int tt = 0; tt < TT; ++tt)
      a[tt] = x[tbase[tt] + nn];
    #pragma unroll
    for (int tt = 0; tt < TT; ++tt)
      #pragma unroll
      for (int kk = 0; kk < KG; ++kk) {
        accr[tt][kk] = fmaf(a[tt], krv[kk], accr[tt][kk]);
        acci[tt][kk] = fmaf(a[tt], kiv[kk], acci[tt][kk]);
      }
  }
  #pragma unroll
  for (int tt = 0; tt < TT; ++tt) {
    #pragma unroll
    for (int kk = 0; kk < KG; ++kk) {
      float r = accr[tt][kk];
      float i = acci[tt][kk];
      #pragma unroll
      for (int s = 32; s > 0; s >>= 1) {
        r += __shfl_xor(r, s, 64);
        i += __shfl_xor(i, s, 64);
      }
      if (lane == 0) {
        const int t = t0 + tt;
        if (t < kT)
          out[(b * kT + t) * kBins + (k0 + kk)] = sqrtf(r * r + i * i);
      }
    }
  }
}
// ============================================================================

extern "C" void kernel_launch(void* const* d_in, const int* in_sizes, int n_in,
                              void* d_out, int out_size, void* d_ws, size_t ws_size,
                              hipStream_t stream) {
  const float* x  = (const float*)d_in[0];   // [4, 1, 352768]
  const float* kr = (const float*)d_in[1];   // [168, nmax]
  const float* ki = (const float*)d_in[2];   // [168, nmax]
  float* out = (float*)d_out;                // [4, 1, 689, 168]

  const int nmax = in_sizes[1] / kBins;      // 23013 (runtime truth)
  const int pad  = nmax - kHop;

  const int kcap = ((nmax + 255) / 256) * 256;   // 23040
  const double Q = 1.0 / (exp2(1.0 / 24.0) - 1.0);

  // ---- path P/A tables ----
  JobsC jc;
  int tot = 0;
  for (int g = 0; g < kG16; ++g) {
    const double f0 = 32.7 * exp2((double)(16 * g) / 24.0);
    const int N = (int)ceil(Q * (double)kSR / f0) + 8;
    int lo = nmax - N;
    if (lo < 0) lo = 0;
    lo &= ~255;
    jc.lo16[g] = lo;
    jc.cb16[g] = tot;
    tot += (kcap - lo) / 32;
  }
  jc.totch = tot;                        // ~1980 chunks
  // ns=11 slice table (R9/R12/R13-verified optimum: 8/2/1, <=96 chunks)
  int ns = 0;
  for (int m = 0; m < 3; ++m) {
    jc.mlo[m] = jc.lo16[4 * m];
    jc.sbeg[m] = ns;
    const int C = (kcap - jc.mlo[m]) / 32;       // 720 / 120 / 24
    const int nsl = (C + 95) / 96;               // 8 / 2 / 1
    const int len = ((C + nsl - 1) / nsl + 1) & ~1;
    for (int s = 0; s < nsl && ns < 24; ++s) {
      const int lo = s * len;
      if (lo >= C) break;
      int hi = lo + len;
      if (hi > C) hi = C;
      jc.sm[ns] = m; jc.slo[ns] = lo; jc.shi[ns] = hi;
      ++ns;
    }
    jc.scnt[m] = ns - jc.sbeg[m];
  }
  jc.ns = ns;                            // 11 expected

  // ---- shared ws pieces ----
  const int xpsA = (kT - 1) * kHop + kcap + 256;           // 375,552 (%8==0)
  const size_t xpA_bytes = (size_t)kB * xpsA * sizeof(_Float16);
  const size_t bpA_bytes = (size_t)tot * 2048;

  // path P layout: xp | part(f16) | bp
  const size_t partP_off   = (xpA_bytes + 511) & ~(size_t)511;
  const size_t partP_bytes = (size_t)ns * kFBB * 4 * 1024 * sizeof(_Float16);
  const size_t bpP_off     = (partP_off + partP_bytes + 511) & ~(size_t)511;
  const size_t ws_P = bpP_off + bpA_bytes;                 // ~14.95 MB

  // path A layout: xp | acc(f32) | bp
  const size_t accA_off  = (xpA_bytes + 511) & ~(size_t)511;
  const size_t accA_bytes = (size_t)kAcc * sizeof(float);
  const size_t bpA_off   = (accA_off + accA_bytes + 511) & ~(size_t)511;
  const size_t ws_A = bpA_off + bpA_bytes;                 // ~10.8 MB

  // path B layout
  const int xpsB = (kTPadB - 1) * kHop + kcap + 256;
  const size_t xpB_bytes = (size_t)kB * xpsB * sizeof(_Float16);
  const size_t accB_off  = (xpB_bytes + 511) & ~(size_t)511;
  const size_t accB_bytes = (size_t)kAccB * sizeof(float);
  const size_t ws_B = accB_off + accB_bytes;

  const int nbx = (kB * (xpsA / 8) + 255) / 256;   // audio blocks (8 el/thr)
  const int nbp = (tot + 3) / 4;                   // bpack blocks (4 chunks ea)

  if (ws_size >= ws_P) {
    // ---- path P: partial-store split-K, no atomics ----
    _Float16* xp   = (_Float16*)d_ws;
    _Float16* part = (_Float16*)((char*)d_ws + partP_off);
    _Float16* bp   = (_Float16*)((char*)d_ws + bpP_off);

    prep_fused<<<nbx + nbp, 256, 0, stream>>>(
        x, kr, ki, xp, bp, (float*)part /*unused*/, pad, xpsA, nmax,
        nbx, nbp, jc);
    {
      dim3 grid(kFBB, ns);
      cqt_mfma_t<true><<<grid, 256, 0, stream>>>(
          bp, xp, nullptr, part, xpsA, jc);
    }
    {
      dim3 grid(kFBB, 3);    // 11 g16 waves per (fb,b) in 3 4-wave WGs
      cqt_mag_part<<<grid, 256, 0, stream>>>(part, out, jc);
    }
    return;
  }

  if (ws_size >= ws_A) {
    // ---- path A: R13 atomic split-K (verified, total ~128us) ----
    _Float16* xp = (_Float16*)d_ws;
    float* accb  = (float*)((char*)d_ws + accA_off);
    _Float16* bp = (_Float16*)((char*)d_ws + bpA_off);

    const int nba = (kAcc / 4 + 255) / 256;
    prep_fused<<<nbx + nbp + nba, 256, 0, stream>>>(
        x, kr, ki, xp, bp, accb, pad, xpsA, nmax, nbx, nbp, jc);
    {
      dim3 grid(kFBB, ns);
      cqt_mfma_t<false><<<grid, 256, 0, stream>>>(
          bp, xp, accb, nullptr, xpsA, jc);
    }
    {
      const int total = kB * kT * kBins;
      cqt_mag4<<<(total / 4 + 255) / 256, 256, 0, stream>>>(accb, out);
    }
    return;
  }

  if (ws_size >= ws_B) {
    // ---- path B (round-3, verified ~224us) ----
    _Float16* xp = (_Float16*)d_ws;
    float* accb  = (float*)((char*)d_ws + accB_off);
    Jobs jt;
    int nj = 0;
    for (int g = 0; g < 11; ++g) {
      const int gk0 = 16 * g;
      const double f0 = 32.7 * exp2((double)gk0 / 24.0);
      const int N = (int)ceil(Q * (double)kSR / f0) + 8;
      int lo = nmax - N;
      if (lo < 0) lo = 0;
      lo = (lo / 2048) * 2048;
      for (int s = lo; s < kcap && nj < 48; s += 2048) {
        jt.k0[nj] = gk0;
        jt.lo[nj] = s;
        jt.hi[nj] = (s + 2048 < kcap) ? s + 2048 : kcap;
        ++nj;
      }
    }
    jt.n = nj;
    hipMemsetAsync(accb, 0, accB_bytes, stream);
    {
      const int total = kB * (xpsB / 2);
      prep_x_kernel<<<(total + 255) / 256, 256, 0, stream>>>(x, xp, pad, xpsB);
    }
    {
      dim3 grid(nj, kTPadB / 256, kB);
      cqt_mfma_kernel<<<grid, 256, 0, stream>>>(kr, ki, xp, accb, nmax, xpsB, jt);
    }
    {
      const int total = kB * kT * kBins;
      cqt_mag_final<<<(total + 255) / 256, 256, 0, stream>>>(
          accb, out, kTPadB, kBinPadB);
    }
    return;
  }

  // ---- path C: fp32 fallback ----
  {
    const int blocks = fb32::kWaves / 4;
    cqt_mag_kernel<<<blocks, 256, 0, stream>>>(x, kr, ki, out, nmax, pad);
  }
}